// Round 5
// baseline (1045.883 us; speedup 1.0000x reference)
//
#include <hip/hip_runtime.h>

// ---------------- constants ----------------
#define NN 2048
#define EE 262144

typedef __attribute__((ext_vector_type(8))) short bf16x8;
typedef __attribute__((ext_vector_type(4))) float f32x4;
typedef unsigned int u32;
typedef unsigned short u16;

__device__ __forceinline__ u16 f2bf(float f){
  u32 u = __builtin_bit_cast(u32, f);
  u32 r = u + 0x7FFFu + ((u >> 16) & 1u);
  return (u16)(r >> 16);
}
__device__ __forceinline__ float bf2f(u16 h){
  u32 u = ((u32)h) << 16;
  return __builtin_bit_cast(float, u);
}
__device__ __forceinline__ int swzb(int byte, int row){ return byte ^ ((row & 7) << 4); }
__device__ __forceinline__ float lrelu(float v){ return v > 0.f ? v : 0.01f * v; }

// ---------------- ws layout (bytes) ----------------
static const size_t WS_WT    = 0;                    // u16 pool (772096 B)
static const size_t WS_EFNN  = 772096;               // u16 E*64
static const size_t WS_ALPHA = WS_EFNN  + 33554432;  // f32 2E ; kvp reuses this after sort
static const size_t WS_H     = WS_ALPHA + 2097152;   // f32 N*96
static const size_t WS_QKV   = WS_H     + 786432;    // f32 N*288 ; P1 reuses this
static const size_t WS_OBUF  = WS_QKV   + 2359296;   // f32 N*96  ; hp1 reuses this
static const size_t WS_TMPA  = WS_OBUF  + 786432;    // f32 N*96  ; hp2 reuses this
static const size_t WS_TMPB  = WS_TMPA  + 786432;    // f32 N*192 ; P2 reuses this
static const size_t WS_X1    = WS_TMPB  + 1572864;   // f32 N*96
static const size_t WS_NUM   = WS_X1    + 786432;    // f32 N*96
static const size_t WS_DEN   = WS_NUM   + 786432;    // f32 N (pad)
static const size_t WS_XS    = WS_DEN   + 8192;      // f32 N*19 (pad) ; smb reuses this
static const size_t WS_HBF   = WS_XS    + 155648;    // (dead)
static const size_t WS_SIDX  = WS_HBF   + 393216;    // int2 2E
static const size_t WS_ALPS  = WS_SIDX  + 4194304;   // f32 2E (sorted alpha)
static const size_t WS_CNT   = WS_ALPS  + 2097152;   // int N
static const size_t WS_OFFS  = WS_CNT   + 8192;      // int N+1 (pad)

// pool element offsets (bf16, weights transposed [Nc][Kpad])
#define IN1T 0
#define IN2T 3072
#define QKVT 12288
#define OUTT 95232
#define FF1T 122880
#define FF2T 178176
#define EIN1T 233472
#define EIN2T 235520
#define AD1T 239616
#define AR1T 243712
#define GC1T 247808
#define GC2T 321536
#define ENAT 358400
#define ENBT 367616
#define ENCT 376832
#define POOL_TOT 386048

// ---------------- weight convert (f32 -> bf16, transposed, K-padded) ----------------
struct CvtJobs {
  const float* src[27];
  int K[27], Nc[27], Kp[27];
  int cum[28];
};

__global__ __launch_bounds__(256) void k_cvt(CvtJobs jb, u16* __restrict__ pool){
  int i = blockIdx.x * 256 + threadIdx.x;
  if (i >= jb.cum[27]) return;
  int j = 0;
  while (i >= jb.cum[j + 1]) j++;
  int loc = i - jb.cum[j];
  int Kp = jb.Kp[j];
  int n = loc / Kp, k = loc - n * Kp;
  float v = (k < jb.K[j]) ? jb.src[j][(size_t)k * jb.Nc[j] + n] : 0.f;
  pool[i] = f2bf(v);
}

__global__ __launch_bounds__(256) void k_xscale(const float* __restrict__ X, const float* __restrict__ ns,
                                                float* __restrict__ xs){
  int i = blockIdx.x * 256 + threadIdx.x;
  if (i < NN * 19) xs[i] = X[i] / ns[i % 19];
}

// ---------------- destination sort (counting sort over 2E edge rows) ----------------
__global__ __launch_bounds__(256) void k_hist(const int* __restrict__ ei, int* __restrict__ cnt){
  int g = blockIdx.x * 256 + threadIdx.x;
  int i1 = (g < EE) ? ei[2*g] : ei[2*(g - EE) + 1];
  atomicAdd(cnt + i1, 1);
}

__global__ __launch_bounds__(256) void k_scan(const int* __restrict__ cnt, int* __restrict__ offs){
  __shared__ int wsum[4], wbase[4];
  int t = threadIdx.x;
  int base = t * 8;
  int c[8]; int T = 0;
  #pragma unroll
  for (int i = 0; i < 8; i++){ c[i] = cnt[base + i]; T += c[i]; }
  int lane = t & 63, wv = t >> 6;
  int inc = T;
  #pragma unroll
  for (int st = 1; st < 64; st <<= 1){
    int v = __shfl_up(inc, st);
    if (lane >= st) inc += v;
  }
  if (lane == 63) wsum[wv] = inc;
  __syncthreads();
  if (t == 0){ int r = 0; for (int w2 = 0; w2 < 4; w2++){ wbase[w2] = r; r += wsum[w2]; } }
  __syncthreads();
  int run = wbase[wv] + inc - T;
  #pragma unroll
  for (int i = 0; i < 8; i++){ offs[base + i] = run; run += c[i]; }
  if (t == 255) offs[2048] = run;
}

__global__ __launch_bounds__(256) void k_scatter(const int* __restrict__ ei, const float* __restrict__ alpha,
    const int* __restrict__ offs, int* __restrict__ rk, int2* __restrict__ sidx, float* __restrict__ alphaS){
  int g = blockIdx.x * 256 + threadIdx.x;
  int i1, i2;
  if (g < EE){ i1 = ei[2*g]; i2 = ei[2*g + 1]; }
  else { int gg = g - EE; i1 = ei[2*gg + 1]; i2 = ei[2*gg]; }
  int r = atomicAdd(rk + i1, 1);
  int pos = offs[i1] + r;
  sidx[pos] = make_int2(i1, i2);
  alphaS[pos] = alpha[g];
}

__global__ __launch_bounds__(256) void k_dens(const int* __restrict__ offs, const float* __restrict__ alphaS,
                                              float* __restrict__ den){
  int n = blockIdx.x * 4 + (threadIdx.x >> 6);
  int lane = threadIdx.x & 63;
  int b = offs[n], e = offs[n + 1];
  float s = 0.f;
  for (int i = b + lane; i < e; i += 64) s += alphaS[i];
  #pragma unroll
  for (int st = 1; st < 64; st <<= 1) s += __shfl_xor(s, st);
  if (lane == 0) den[n] = s + (n == 0 ? 2048.f : 0.f);
}

// ---------------- MFMA tile helpers ----------------
template<int NT, int KS, int SR>
__device__ __forceinline__ void tile_gemm(const char* sm, int aBase, int bBase, int lane, f32x4* acc){
  const int r15 = lane & 15;
  const int kb = (lane >> 4) * 16;
  #pragma unroll
  for (int ks = 0; ks < KS; ks++){
    bf16x8 a = *(const bf16x8*)(sm + aBase + swzb(r15*SR + ks*64 + kb, r15));
    #pragma unroll
    for (int ct = 0; ct < NT; ct++){
      int n = ct*16 + r15;
      bf16x8 b = *(const bf16x8*)(sm + bBase + swzb(n*SR + ks*64 + kb, n));
      acc[ct] = __builtin_amdgcn_mfma_f32_16x16x32_bf16(a, b, acc[ct], 0, 0, 0);
    }
  }
}

// B directly from global (L2-hot weight pool), un-swizzled [Nc][Kp] bf16
template<int NT, int KS, int SR>
__device__ __forceinline__ void tile_gemm_gb(const char* sm, int aBase, const u16* __restrict__ W, int Kp,
                                             int lane, f32x4* acc){
  const int r15 = lane & 15;
  const int kb = (lane >> 4) * 16;
  const int ke = (lane >> 4) * 8;
  #pragma unroll
  for (int ks = 0; ks < KS; ks++){
    bf16x8 a = *(const bf16x8*)(sm + aBase + swzb(r15*SR + ks*64 + kb, r15));
    #pragma unroll
    for (int ct = 0; ct < NT; ct++){
      int n = ct*16 + r15;
      bf16x8 b = *(const bf16x8*)(W + n*Kp + ks*32 + ke);
      acc[ct] = __builtin_amdgcn_mfma_f32_16x16x32_bf16(a, b, acc[ct], 0, 0, 0);
    }
  }
}

// ---------------- generic GEMM: C[M][Nc] = act(A[M][K] @ W + bias), M mult of 64 ----------------
template<int NT, int KS, int ACT>
__global__ __launch_bounds__(256) void k_gemm(const float* __restrict__ A, int K,
    const u16* __restrict__ Wt, const float* __restrict__ bias, float* __restrict__ C)
{
  constexpr int Kpad = KS * 32;
  constexpr int Nc = NT * 16;
  constexpr int SR = (Kpad*2 + 127) / 128 * 128;
  constexpr int ABASE = Nc * SR;
  __shared__ __align__(16) char smem[Nc*SR + 64*SR];
  constexpr int KP8 = Kpad / 8;
  for (int j = threadIdx.x; j < Nc*KP8; j += 256){
    int n = j / KP8;
    *(uint4*)(smem + swzb(n*SR + (j - n*KP8)*16, n)) = ((const uint4*)Wt)[j];
  }
  const int row0 = blockIdx.x * 64;
  for (int j = threadIdx.x; j < 64*(Kpad/2); j += 256){
    int r = j / (Kpad/2); int c = (j - r*(Kpad/2)) * 2;
    const float* ap = A + (size_t)(row0 + r)*K + c;
    float f0 = (c < K) ? ap[0] : 0.f;
    float f1 = (c + 1 < K) ? ap[1] : 0.f;
    *(u32*)(smem + ABASE + swzb(r*SR + c*2, r)) = (u32)f2bf(f0) | ((u32)f2bf(f1) << 16);
  }
  __syncthreads();
  const int lane = threadIdx.x & 63, w = threadIdx.x >> 6;
  const int r15 = lane & 15;
  f32x4 acc[NT] = {};
  tile_gemm<NT, KS, SR>(smem, ABASE + w*16*SR, 0, lane, acc);
  #pragma unroll
  for (int ct = 0; ct < NT; ct++){
    int col = ct*16 + r15;
    float bs = bias ? bias[col] : 0.f;
    #pragma unroll
    for (int q = 0; q < 4; q++){
      int r = row0 + w*16 + (lane >> 4)*4 + q;
      float v = acc[ct][q] + bs;
      if (ACT == 1) v = lrelu(v);
      if (ACT == 2) v = v > 0.f ? v : 0.f;
      C[(size_t)r*Nc + col] = v;
    }
  }
}

// ---------------- LayerNorm(a+b) ----------------
__global__ __launch_bounds__(256) void k_ln(const float* __restrict__ A, const float* __restrict__ B,
    const float* __restrict__ sc, const float* __restrict__ bi, float* __restrict__ out)
{
  const int row = blockIdx.x*4 + (threadIdx.x >> 6);
  const int lane = threadIdx.x & 63;
  const float* ap = A + row*96; const float* bp = B + row*96;
  float v1 = ap[lane] + bp[lane];
  float v2 = (lane < 32) ? (ap[64+lane] + bp[64+lane]) : 0.f;
  float sum = v1 + v2, sq = v1*v1 + v2*v2;
  #pragma unroll
  for (int st = 1; st < 64; st <<= 1){ sum += __shfl_xor(sum, st); sq += __shfl_xor(sq, st); }
  float mean = sum * (1.f/96.f);
  float var = sq * (1.f/96.f) - mean*mean;
  float rs = rsqrtf(var + 1e-5f);
  out[row*96 + lane] = (v1 - mean)*rs*sc[lane] + bi[lane];
  if (lane < 32) out[row*96 + 64 + lane] = (v2 - mean)*rs*sc[64+lane] + bi[64+lane];
}

// ---------------- attention v3: packed KV, 4-way key-split grid, atomic combine ----------------
// kvp[h][j][16] = {K[0..8), V[0..8)} f32 -- one 64B line per key
__global__ __launch_bounds__(256) void k_kvpack(const float* __restrict__ qkv, float* __restrict__ kvp){
  int i = blockIdx.x * 256 + threadIdx.x;      // 12*2048*16
  int c = i & 15, j = (i >> 4) & 2047, h = i >> 15;
  kvp[i] = qkv[(size_t)j*288 + (c < 8 ? 96 + h*8 + c : 184 + h*8 + c)];
}

__global__ __launch_bounds__(256) void k_attn3(const float* __restrict__ qkv, const float* __restrict__ kvp,
                                               float* __restrict__ obuf, float* __restrict__ smb){
  __shared__ float part[4][64][13];
  const int tid = threadIdx.x;
  const int lane = tid & 63, w = tid >> 6;
  const int b = blockIdx.x;
  const int head = b >> 7, rem = b & 127;
  const int rb = rem >> 2, ks = rem & 3;
  const int row = rb*64 + lane;
  const float* qp = qkv + (size_t)row*288 + head*8;
  float4 qa = *(const float4*)qp;
  float4 qb = *(const float4*)(qp + 4);
  const float* kv = kvp + ((size_t)head*2048 + ks*512 + w*128)*16;
  float sm = 0.f;
  float o0=0,o1=0,o2=0,o3=0,o4=0,o5=0,o6=0,o7=0;
  #pragma unroll 4
  for (int j = 0; j < 128; j++){
    const float* kp = kv + j*16;
    float4 ka = *(const float4*)kp;
    float4 kb = *(const float4*)(kp + 4);
    float4 va = *(const float4*)(kp + 8);
    float4 vb = *(const float4*)(kp + 12);
    float s = qa.x*ka.x + qa.y*ka.y + qa.z*ka.z + qa.w*ka.w
            + qb.x*kb.x + qb.y*kb.y + qb.z*kb.z + qb.w*kb.w;
    s = fminf(s * 0.35355339059327373f, 60.f);
    float p = __expf(s);
    sm += p;
    o0 += p*va.x; o1 += p*va.y; o2 += p*va.z; o3 += p*va.w;
    o4 += p*vb.x; o5 += p*vb.y; o6 += p*vb.z; o7 += p*vb.w;
  }
  float* pp = part[w][lane];
  pp[0]=o0; pp[1]=o1; pp[2]=o2; pp[3]=o3; pp[4]=o4; pp[5]=o5; pp[6]=o6; pp[7]=o7; pp[8]=sm;
  __syncthreads();
  if (w == 0){
    float t[9];
    #pragma unroll
    for (int d = 0; d < 9; d++)
      t[d] = part[0][lane][d] + part[1][lane][d] + part[2][lane][d] + part[3][lane][d];
    float* op = obuf + (size_t)row*96 + head*8;
    #pragma unroll
    for (int d = 0; d < 8; d++) atomicAdd(op + d, t[d]);
    atomicAdd(smb + row*12 + head, t[8]);
  }
}

__global__ __launch_bounds__(256) void k_attn_norm(const float* __restrict__ smb, float* __restrict__ obuf){
  int i = blockIdx.x * 256 + threadIdx.x;      // N*96
  int row = i / 96, c = i - row*96;
  obuf[i] = obuf[i] / smb[row*12 + (c >> 3)];
}

// ---------------- fused edge MLPs: ef -> ein1 -> ein2 (efnn) -> {ad, ar} -> alpha ----------------
__global__ __launch_bounds__(256) void k_edge(const float* __restrict__ efr, const float* __restrict__ es,
    const u16* __restrict__ pool,
    const float* __restrict__ eb1, const float* __restrict__ eb2,
    const float* __restrict__ adb1, const float* __restrict__ adw2, const float* __restrict__ adb2,
    const float* __restrict__ arb1, const float* __restrict__ arw2, const float* __restrict__ arb2,
    u16* __restrict__ efnn, float* __restrict__ alpha)
{
  __shared__ __align__(16) char smem[49152];
  const int tid = threadIdx.x;
  const int e0 = blockIdx.x * 64;
  for (int j = tid; j < 256; j += 256){
    int n = j >> 2;
    *(uint4*)(smem + swzb(n*128 + (j&3)*16, n)) = ((const uint4*)(pool + EIN1T))[j];
  }
  for (int j = tid; j < 512; j += 256){
    int n = j >> 3; int b = n*128 + (j&7)*16;
    *(uint4*)(smem + 8192  + swzb(b, n)) = ((const uint4*)(pool + EIN2T))[j];
    *(uint4*)(smem + 16384 + swzb(b, n)) = ((const uint4*)(pool + AD1T))[j];
    *(uint4*)(smem + 24576 + swzb(b, n)) = ((const uint4*)(pool + AR1T))[j];
  }
  for (int j = tid; j < 64*16; j += 256){
    int r = j >> 4; int c = (j & 15) * 2;
    float f0 = 0.f, f1 = 0.f;
    if (c < 12)     f0 = (efr[(e0+r)*12 + c]     + 1e-4f) / es[c];
    if (c + 1 < 12) f1 = (efr[(e0+r)*12 + c + 1] + 1e-4f) / es[c+1];
    *(u32*)(smem + 32768 + swzb(r*128 + c*2, r)) = (u32)f2bf(f0) | ((u32)f2bf(f1) << 16);
  }
  __syncthreads();
  const int lane = tid & 63, w = tid >> 6;
  const int r15 = lane & 15;

  auto store_lds = [&](f32x4* acc, int base, const float* bias){
    #pragma unroll
    for (int ct = 0; ct < 4; ct++){
      int col = ct*16 + r15;
      float bs = bias[col];
      #pragma unroll
      for (int q = 0; q < 4; q++){
        int row = w*16 + (lane >> 4)*4 + q;
        *(u16*)(smem + base + swzb(row*128 + col*2, row)) = f2bf(lrelu(acc[ct][q] + bs));
      }
    }
  };

  { f32x4 acc[4] = {};
    tile_gemm<4,1,128>(smem, 32768 + w*2048, 0, lane, acc);
    store_lds(acc, 40960, eb1); }
  { f32x4 acc[4] = {};
    tile_gemm<4,2,128>(smem, 40960 + w*2048, 8192, lane, acc);
    store_lds(acc, 32768, eb2); }
  __syncthreads();
  for (int j = tid; j < 2048; j += 256){
    int r = j >> 5;
    ((u32*)efnn)[e0*32 + j] = *(const u32*)(smem + 32768 + swzb(r*128 + (j&31)*4, r));
  }
  { f32x4 acc[4] = {};
    tile_gemm<4,2,128>(smem, 32768 + w*2048, 16384, lane, acc);
    store_lds(acc, 40960, adb1); }
  __syncthreads();
  { int row = tid >> 2, part = tid & 3;
    float s = 0.f;
    #pragma unroll
    for (int i = 0; i < 16; i++){
      int k = part*16 + i;
      s += bf2f(*(const u16*)(smem + 40960 + swzb(row*128 + k*2, row))) * adw2[k];
    }
    s += __shfl_xor(s, 1); s += __shfl_xor(s, 2);
    if (part == 0) alpha[e0 + row] = 1.f / (1.f + __expf(-(s + adb2[0]))); }
  __syncthreads();
  { f32x4 acc[4] = {};
    tile_gemm<4,2,128>(smem, 32768 + w*2048, 24576, lane, acc);
    store_lds(acc, 40960, arb1); }
  __syncthreads();
  { int row = tid >> 2, part = tid & 3;
    float s = 0.f;
    #pragma unroll
    for (int i = 0; i < 16; i++){
      int k = part*16 + i;
      s += bf2f(*(const u16*)(smem + 40960 + swzb(row*128 + k*2, row))) * arw2[k];
    }
    s += __shfl_xor(s, 1); s += __shfl_xor(s, 2);
    if (part == 0) alpha[EE + e0 + row] = 1.f / (1.f + __expf(-(s + arb2[0]))); }
}

// ---------------- graph-conv v3: h1 = lrelu(P1[i1]+P2[i2]) -> GEMM2 -> segment scan ----------------
__global__ __launch_bounds__(256) void k_gc3(const float* __restrict__ P1, const float* __restrict__ P2,
    const int2* __restrict__ sidx, const float* __restrict__ alphaS, const u16* __restrict__ wt2,
    const float* __restrict__ b2, float* __restrict__ num)
{
  __shared__ __align__(16) char smem[51712];
  int*   nid  = (int*)(smem + 50176);
  int*   i2s  = (int*)(smem + 50688);
  float* alph = (float*)(smem + 51200);
  const int tid = threadIdx.x;
  const int row0 = blockIdx.x * 128;
  if (tid < 128){
    int2 p = sidx[row0 + tid];
    nid[tid] = p.x; i2s[tid] = p.y;
    alph[tid] = alphaS[row0 + tid];
  }
  __syncthreads();
  // h1 = lrelu(P1[i1] + P2[i2]) -> LDS bf16 [128][384B swz]
  for (int j = tid; j < 128*24; j += 256){
    int r = j / 24, q = j - (j/24)*24;
    int c8 = q * 8;
    const float* p1 = P1 + (size_t)nid[r]*192 + c8;
    const float* p2 = P2 + (size_t)i2s[r]*192 + c8;
    float4 a0 = *(const float4*)p1, a1 = *(const float4*)(p1 + 4);
    float4 b0 = *(const float4*)p2, b1 = *(const float4*)(p2 + 4);
    u16 pk[8];
    pk[0]=f2bf(lrelu(a0.x+b0.x)); pk[1]=f2bf(lrelu(a0.y+b0.y));
    pk[2]=f2bf(lrelu(a0.z+b0.z)); pk[3]=f2bf(lrelu(a0.w+b0.w));
    pk[4]=f2bf(lrelu(a1.x+b1.x)); pk[5]=f2bf(lrelu(a1.y+b1.y));
    pk[6]=f2bf(lrelu(a1.z+b1.z)); pk[7]=f2bf(lrelu(a1.w+b1.w));
    *(bf16x8*)(smem + swzb(r*384 + c8*2, r)) = *(bf16x8*)pk;
  }
  __syncthreads();
  const int lane = tid & 63, w = tid >> 6;
  const int wr = w >> 1, wc = w & 1;
  const int r15 = lane & 15;
  const int kb = (lane >> 4) * 16;
  const int ke = (lane >> 4) * 8;
  f32x4 acc2[4][3] = {};
  #pragma unroll
  for (int ks = 0; ks < 6; ks++){
    bf16x8 a[4];
    #pragma unroll
    for (int rt = 0; rt < 4; rt++){
      int row = wr*64 + rt*16 + r15;
      a[rt] = *(const bf16x8*)(smem + swzb(row*384 + ks*64 + kb, row));
    }
    #pragma unroll
    for (int ct = 0; ct < 3; ct++){
      int n = wc*48 + ct*16 + r15;
      bf16x8 b = *(const bf16x8*)(wt2 + n*192 + ks*32 + ke);
      #pragma unroll
      for (int rt = 0; rt < 4; rt++)
        acc2[rt][ct] = __builtin_amdgcn_mfma_f32_16x16x32_bf16(a[rt], b, acc2[rt][ct], 0, 0, 0);
    }
  }
  __syncthreads();
  #pragma unroll
  for (int ct = 0; ct < 3; ct++){
    int col = wc*48 + ct*16 + r15;
    float bs = b2[col];
    #pragma unroll
    for (int rt = 0; rt < 4; rt++){
      #pragma unroll
      for (int q = 0; q < 4; q++){
        int row = wr*64 + rt*16 + (lane >> 4)*4 + q;
        *(float*)(smem + row*392 + col*4) = alph[row] * lrelu(acc2[rt][ct][q] + bs);
      }
    }
  }
  __syncthreads();
  if (tid < 192){
    int hf = tid / 96;
    int c = tid - hf*96;
    int rbeg = hf*64, rend = rbeg + 64;
    float accv = 0.f;
    int cur = nid[rbeg];
    for (int r = rbeg; r < rend; r++){
      int n2 = nid[r];
      if (n2 != cur){ atomicAdd(num + cur*96 + c, accv); accv = 0.f; cur = n2; }
      accv += *(const float*)(smem + r*392 + c*4);
    }
    atomicAdd(num + cur*96 + c, accv);
  }
}

// the N rows with ind1=ind2=0 are identical: compute once, add 2048x
__global__ __launch_bounds__(256) void k_gcnode0(const float* __restrict__ h,
    const float* __restrict__ W1, const float* __restrict__ b1,
    const float* __restrict__ W2, const float* __restrict__ b2, float* __restrict__ num)
{
  __shared__ float in_s[192], h1_s[192];
  int t = threadIdx.x;
  if (t < 192) in_s[t] = h[t % 96];
  __syncthreads();
  if (t < 192){
    float s = b1[t];
    for (int k = 0; k < 192; k++) s += in_s[k] * W1[k*192 + t];
    h1_s[t] = lrelu(s);
  }
  __syncthreads();
  if (t < 96){
    float s = b2[t];
    for (int k = 0; k < 192; k++) s += h1_s[k] * W2[k*96 + t];
    num[t] += 2048.f * lrelu(s);
  }
}

__global__ __launch_bounds__(256) void k_hupd(const float* __restrict__ num, const float* __restrict__ den,
                                              float* __restrict__ h){
  int i = blockIdx.x * 256 + threadIdx.x;
  h[i] = num[i] / (den[i / 96] + 1e-8f);
}

// ---------------- final predictor v2 ----------------
__global__ __launch_bounds__(256) void k_final2(const float* __restrict__ hp1, const float* __restrict__ hp2,
    const int* __restrict__ ei, const u16* __restrict__ efnn, const float* __restrict__ efr,
    const float* __restrict__ es, const u16* __restrict__ enc,
    const float* __restrict__ enw2, const float* __restrict__ enb2, float* __restrict__ out)
{
  __shared__ __align__(16) char smem[38144];
  float* etb = (float*)(smem + 12288);
  float* w2s = (float*)(smem + 37120);
  int*   eix = (int*)  (smem + 37504);
  const int tid = threadIdx.x;
  const int e0 = blockIdx.x * 64;
  for (int j = tid; j < 768; j += 256){
    int r = j / 12, q = j - (j/12)*12;
    int e = e0 + r;
    bf16x8 v;
    if (q < 8){
      v = *(const bf16x8*)(efnn + (size_t)e*64 + q*8);
    } else if (q < 10){
      u16 pk[8];
      #pragma unroll
      for (int i = 0; i < 8; i++){
        int cc = (q - 8)*8 + i;
        pk[i] = (cc < 12) ? f2bf((efr[(size_t)e*12 + cc] + 1e-4f) / es[cc]) : (u16)0;
      }
      v = *(bf16x8*)pk;
    } else {
      v = bf16x8{0,0,0,0,0,0,0,0};
    }
    *(bf16x8*)(smem + swzb(r*192 + q*16, r)) = v;
  }
  if (tid < 96) w2s[tid] = enw2[tid];
  if (tid < 64){ eix[2*tid] = ei[2*(e0+tid)]; eix[2*tid+1] = ei[2*(e0+tid)+1]; }
  __syncthreads();
  const int lane = tid & 63, w = tid >> 6;
  const int r15 = lane & 15;
  f32x4 acc[6] = {};
  tile_gemm_gb<6,3,192>(smem, w*16*192, enc, 96, lane, acc);
  #pragma unroll
  for (int ct = 0; ct < 6; ct++){
    int col = ct*16 + r15;
    #pragma unroll
    for (int q = 0; q < 4; q++){
      int row = w*16 + (lane >> 4)*4 + q;
      etb[row*97 + col] = acc[ct][q];
    }
  }
  __syncthreads();
  int r = tid >> 2, part = tid & 3;
  int s1 = eix[2*r], s2 = eix[2*r + 1];
  const float* p1 = hp1 + (size_t)s1*96 + part*24;
  const float* p2 = hp2 + (size_t)s2*96 + part*24;
  const float* et = etb + r*97 + part*24;
  const float* wz = w2s + part*24;
  float s = 0.f;
  #pragma unroll
  for (int i = 0; i < 24; i++){
    float v = et[i] + p1[i] + p2[i];
    s += lrelu(v) * wz[i];
  }
  s += __shfl_xor(s, 1); s += __shfl_xor(s, 2);
  if (part == 0) out[e0 + r] = 1.f / (1.f + __expf(-(s + enb2[0])));
}

// ---------------- host ----------------
extern "C" void kernel_launch(void* const* d_in, const int* in_sizes, int n_in,
                              void* d_out, int out_size, void* d_ws, size_t ws_size,
                              hipStream_t stream) {
  (void)in_sizes; (void)n_in; (void)out_size; (void)ws_size;
  const float* X      = (const float*)d_in[0];
  const float* EFR    = (const float*)d_in[1];
  const int*   EI     = (const int*)  d_in[2];
  const float* NS     = (const float*)d_in[3];
  const float* ES     = (const float*)d_in[4];
  const float* IN_W1  = (const float*)d_in[5];
  const float* IN_B1  = (const float*)d_in[6];
  const float* IN_W2  = (const float*)d_in[7];
  const float* IN_B2  = (const float*)d_in[8];
  const float* QKV_W  = (const float*)d_in[9];
  const float* QKV_B  = (const float*)d_in[10];
  const float* OUT_W  = (const float*)d_in[11];
  const float* OUT_B  = (const float*)d_in[12];
  const float* LN1S   = (const float*)d_in[13];
  const float* LN1B   = (const float*)d_in[14];
  const float* FFW1   = (const float*)d_in[15];
  const float* FFB1   = (const float*)d_in[16];
  const float* FFW2   = (const float*)d_in[17];
  const float* FFB2   = (const float*)d_in[18];
  const float* LN2S   = (const float*)d_in[19];
  const float* LN2B   = (const float*)d_in[20];
  const float* EIN_W1 = (const float*)d_in[21];
  const float* EIN_B1 = (const float*)d_in[22];
  const float* EIN_W2 = (const float*)d_in[23];
  const float* EIN_B2 = (const float*)d_in[24];
  const float* AD_W1  = (const float*)d_in[25];
  const float* AD_B1  = (const float*)d_in[26];
  const float* AD_W2  = (const float*)d_in[27];
  const float* AD_B2  = (const float*)d_in[28];
  const float* AR_W1  = (const float*)d_in[29];
  const float* AR_B1  = (const float*)d_in[30];
  const float* AR_W2  = (const float*)d_in[31];
  const float* AR_B2  = (const float*)d_in[32];
  const float* GC_W1  = (const float*)d_in[33];
  const float* GC_B1  = (const float*)d_in[34];
  const float* GC_W2  = (const float*)d_in[35];
  const float* GC_B2  = (const float*)d_in[36];
  const float* EN_W1  = (const float*)d_in[37];
  const float* EN_B1  = (const float*)d_in[38];
  const float* EN_W2  = (const float*)d_in[39];
  const float* EN_B2  = (const float*)d_in[40];

  char* ws = (char*)d_ws;
  u16*   pool   = (u16*)  (ws + WS_WT);
  u16*   efnn   = (u16*)  (ws + WS_EFNN);
  float* alpha  = (float*)(ws + WS_ALPHA);
  float* h      = (float*)(ws + WS_H);
  float* qkvb   = (float*)(ws + WS_QKV);
  float* obuf   = (float*)(ws + WS_OBUF);
  float* tmpA   = (float*)(ws + WS_TMPA);
  float* tmpB   = (float*)(ws + WS_TMPB);
  float* x1     = (float*)(ws + WS_X1);
  float* num    = (float*)(ws + WS_NUM);
  float* den    = (float*)(ws + WS_DEN);
  float* xs     = (float*)(ws + WS_XS);
  int2*  sidx   = (int2*) (ws + WS_SIDX);
  float* alphaS = (float*)(ws + WS_ALPS);
  int*   cnt    = (int*)  (ws + WS_CNT);
  int*   offs   = (int*)  (ws + WS_OFFS);
  float* P1     = (float*)(ws + WS_QKV);   // reuse (encoders done before gc)
  float* P2     = (float*)(ws + WS_TMPB);
  float* hp1    = (float*)(ws + WS_OBUF);
  float* hp2    = (float*)(ws + WS_TMPA);
  float* kvp    = (float*)(ws + WS_ALPHA); // reuse: alpha dead after k_scatter
  float* smb    = (float*)(ws + WS_XS);    // reuse: xs dead after embedding

  // ---- weight conversion jobs ----
  CvtJobs jb;
  int idx = 0, cum = 0;
  auto addjob = [&](const float* s, int K, int Nc, int Kp){
    jb.src[idx] = s; jb.K[idx] = K; jb.Nc[idx] = Nc; jb.Kp[idx] = Kp;
    jb.cum[idx] = cum; cum += Nc * Kp; idx++;
  };
  addjob(IN_W1, 19, 96, 32);
  addjob(IN_W2, 96, 96, 96);
  for (int l = 0; l < 3; l++) addjob(QKV_W + (size_t)l*96*288, 96, 288, 96);
  for (int l = 0; l < 3; l++) addjob(OUT_W + (size_t)l*96*96,  96, 96,  96);
  for (int l = 0; l < 3; l++) addjob(FFW1  + (size_t)l*96*192, 96, 192, 96);
  for (int l = 0; l < 3; l++) addjob(FFW2  + (size_t)l*192*96, 192, 96, 192);
  addjob(EIN_W1, 12, 64, 32);
  addjob(EIN_W2, 64, 64, 64);
  addjob(AD_W1,  64, 64, 64);
  addjob(AR_W1,  64, 64, 64);
  for (int i = 0; i < 2; i++){
    addjob(GC_W1 + (size_t)i*192*192,          96, 192, 96);
    addjob(GC_W1 + (size_t)i*192*192 + 96*192, 96, 192, 96);
  }
  for (int i = 0; i < 2; i++) addjob(GC_W2 + (size_t)i*192*96, 192, 96, 192);
  addjob(EN_W1,            96, 96, 96);
  addjob(EN_W1 + 96*96,    96, 96, 96);
  addjob(EN_W1 + 192*96,   76, 96, 96);
  jb.cum[idx] = cum;

  k_cvt<<<(POOL_TOT + 255)/256, 256, 0, stream>>>(jb, pool);

  // ---- node embedding ----
  k_xscale<<<(NN*19 + 255)/256, 256, 0, stream>>>(X, NS, xs);
  k_gemm<6,1,1><<<32, 256, 0, stream>>>(xs, 19, pool + IN1T, IN_B1, tmpA);
  k_gemm<6,3,1><<<32, 256, 0, stream>>>(tmpA, 96, pool + IN2T, IN_B2, h);

  // ---- edge MLPs + attention weights ----
  k_edge<<<EE/64, 256, 0, stream>>>(EFR, ES, pool, EIN_B1, EIN_B2,
                                    AD_B1, AD_W2, AD_B2, AR_B1, AR_W2, AR_B2, efnn, alpha);

  // ---- destination sort + den ----
  (void)hipMemsetAsync(cnt, 0, NN*4, stream);
  k_hist<<<(2*EE)/256, 256, 0, stream>>>(EI, cnt);
  k_scan<<<1, 256, 0, stream>>>(cnt, offs);
  (void)hipMemsetAsync(cnt, 0, NN*4, stream);
  k_scatter<<<(2*EE)/256, 256, 0, stream>>>(EI, alpha, offs, cnt, sidx, alphaS);
  k_dens<<<NN/4, 256, 0, stream>>>(offs, alphaS, den);

  // ---- 3 encoder layers ----
  for (int l = 0; l < 3; l++){
    k_gemm<18,3,0><<<32, 256, 0, stream>>>(h, 96, pool + QKVT + l*27648, QKV_B + l*288, qkvb);
    k_kvpack<<<(12*2048*16)/256, 256, 0, stream>>>(qkvb, kvp);
    (void)hipMemsetAsync(obuf, 0, NN*96*4, stream);
    (void)hipMemsetAsync(smb, 0, NN*12*4, stream);
    k_attn3<<<1536, 256, 0, stream>>>(qkvb, kvp, obuf, smb);
    k_attn_norm<<<(NN*96)/256, 256, 0, stream>>>(smb, obuf);
    k_gemm<6,3,0><<<32, 256, 0, stream>>>(obuf, 96, pool + OUTT + l*9216, OUT_B + l*96, tmpA);
    k_ln<<<512, 256, 0, stream>>>(h, tmpA, LN1S + l*96, LN1B + l*96, x1);
    k_gemm<12,3,2><<<32, 256, 0, stream>>>(x1, 96, pool + FF1T + l*18432, FFB1 + l*192, tmpB);
    k_gemm<6,6,0><<<32, 256, 0, stream>>>(tmpB, 192, pool + FF2T + l*18432, FFB2 + l*96, tmpA);
    k_ln<<<512, 256, 0, stream>>>(x1, tmpA, LN2S + l*96, LN2B + l*96, h);
  }

  // ---- 2 graph-conv iterations ----
  for (int it = 0; it < 2; it++){
    k_gemm<12,3,0><<<32, 256, 0, stream>>>(h, 96, pool + GC1T + it*36864,         nullptr,        P1);
    k_gemm<12,3,0><<<32, 256, 0, stream>>>(h, 96, pool + GC1T + it*36864 + 18432, GC_B1 + it*192, P2);
    (void)hipMemsetAsync(num, 0, NN*96*4, stream);
    k_gc3<<<(2*EE)/128, 256, 0, stream>>>(P1, P2, sidx, alphaS,
        pool + GC2T + it*18432, GC_B2 + it*96, num);
    k_gcnode0<<<1, 256, 0, stream>>>(h, GC_W1 + (size_t)it*192*192, GC_B1 + it*192,
                                     GC_W2 + (size_t)it*192*96, GC_B2 + it*96, num);
    k_hupd<<<(NN*96)/256, 256, 0, stream>>>(num, den, h);
  }

  // ---- final predictor ----
  k_gemm<6,3,0><<<32, 256, 0, stream>>>(h, 96, pool + ENAT, nullptr, hp1);
  k_gemm<6,3,0><<<32, 256, 0, stream>>>(h, 96, pool + ENBT, EN_B1, hp2);
  k_final2<<<EE/64, 256, 0, stream>>>(hp1, hp2, EI, efnn, EFR, ES,
                                      pool + ENCT, EN_W2, EN_B2, (float*)d_out);
}

// Round 6
// 1032.686 us; speedup vs baseline: 1.0128x; 1.0128x over previous
//
#include <hip/hip_runtime.h>

// ---------------- constants ----------------
#define NN 2048
#define EE 262144

typedef __attribute__((ext_vector_type(8))) short bf16x8;
typedef __attribute__((ext_vector_type(4))) float f32x4;
typedef unsigned int u32;
typedef unsigned short u16;

__device__ __forceinline__ u16 f2bf(float f){
  u32 u = __builtin_bit_cast(u32, f);
  u32 r = u + 0x7FFFu + ((u >> 16) & 1u);
  return (u16)(r >> 16);
}
__device__ __forceinline__ float bf2f(u16 h){
  u32 u = ((u32)h) << 16;
  return __builtin_bit_cast(float, u);
}
__device__ __forceinline__ int swzb(int byte, int row){ return byte ^ ((row & 7) << 4); }
__device__ __forceinline__ float lrelu(float v){ return v > 0.f ? v : 0.01f * v; }

// ---------------- ws layout (bytes) ----------------
static const size_t WS_WT    = 0;                    // u16 pool (772096 B)
static const size_t WS_EFNN  = 772096;               // u16 E*64
static const size_t WS_ALPHA = WS_EFNN  + 33554432;  // f32 2E ; kvp reuses this after sort
static const size_t WS_H     = WS_ALPHA + 2097152;   // f32 N*96
static const size_t WS_QKV   = WS_H     + 786432;    // f32 N*288 ; P1 reuses this
static const size_t WS_OBUF  = WS_QKV   + 2359296;   // f32 N*96  ; hp1 reuses this
static const size_t WS_TMPA  = WS_OBUF  + 786432;    // f32 N*96  ; hp2 reuses this
static const size_t WS_TMPB  = WS_TMPA  + 786432;    // f32 N*192 ; P2 reuses this
static const size_t WS_X1    = WS_TMPB  + 1572864;   // f32 N*96
static const size_t WS_NUM   = WS_X1    + 786432;    // f32 N*96
static const size_t WS_DEN   = WS_NUM   + 786432;    // f32 N (pad)
static const size_t WS_XS    = WS_DEN   + 8192;      // f32 N*19 (pad)
static const size_t WS_HBF   = WS_XS    + 155648;    // (dead)
static const size_t WS_SIDX  = WS_HBF   + 393216;    // int2 2E
static const size_t WS_ALPS  = WS_SIDX  + 4194304;   // f32 2E (sorted alpha)
static const size_t WS_CNT   = WS_ALPS  + 2097152;   // int N
static const size_t WS_OFFS  = WS_CNT   + 8192;      // int N+1 (pad)

// pool element offsets (bf16, weights transposed [Nc][Kpad])
#define IN1T 0
#define IN2T 3072
#define QKVT 12288
#define OUTT 95232
#define FF1T 122880
#define FF2T 178176
#define EIN1T 233472
#define EIN2T 235520
#define AD1T 239616
#define AR1T 243712
#define GC1T 247808
#define GC2T 321536
#define ENAT 358400
#define ENBT 367616
#define ENCT 376832
#define POOL_TOT 386048

// ---------------- weight convert (f32 -> bf16, transposed, K-padded) ----------------
struct CvtJobs {
  const float* src[27];
  int K[27], Nc[27], Kp[27];
  int cum[28];
};

__global__ __launch_bounds__(256) void k_cvt(CvtJobs jb, u16* __restrict__ pool){
  int i = blockIdx.x * 256 + threadIdx.x;
  if (i >= jb.cum[27]) return;
  int j = 0;
  while (i >= jb.cum[j + 1]) j++;
  int loc = i - jb.cum[j];
  int Kp = jb.Kp[j];
  int n = loc / Kp, k = loc - n * Kp;
  float v = (k < jb.K[j]) ? jb.src[j][(size_t)k * jb.Nc[j] + n] : 0.f;
  pool[i] = f2bf(v);
}

__global__ __launch_bounds__(256) void k_xscale(const float* __restrict__ X, const float* __restrict__ ns,
                                                float* __restrict__ xs){
  int i = blockIdx.x * 256 + threadIdx.x;
  if (i < NN * 19) xs[i] = X[i] / ns[i % 19];
}

// ---------------- destination sort (counting sort over 2E edge rows) ----------------
__global__ __launch_bounds__(256) void k_hist(const int* __restrict__ ei, int* __restrict__ cnt){
  int g = blockIdx.x * 256 + threadIdx.x;
  int i1 = (g < EE) ? ei[2*g] : ei[2*(g - EE) + 1];
  atomicAdd(cnt + i1, 1);
}

__global__ __launch_bounds__(256) void k_scan(const int* __restrict__ cnt, int* __restrict__ offs){
  __shared__ int wsum[4], wbase[4];
  int t = threadIdx.x;
  int base = t * 8;
  int c[8]; int T = 0;
  #pragma unroll
  for (int i = 0; i < 8; i++){ c[i] = cnt[base + i]; T += c[i]; }
  int lane = t & 63, wv = t >> 6;
  int inc = T;
  #pragma unroll
  for (int st = 1; st < 64; st <<= 1){
    int v = __shfl_up(inc, st);
    if (lane >= st) inc += v;
  }
  if (lane == 63) wsum[wv] = inc;
  __syncthreads();
  if (t == 0){ int r = 0; for (int w2 = 0; w2 < 4; w2++){ wbase[w2] = r; r += wsum[w2]; } }
  __syncthreads();
  int run = wbase[wv] + inc - T;
  #pragma unroll
  for (int i = 0; i < 8; i++){ offs[base + i] = run; run += c[i]; }
  if (t == 255) offs[2048] = run;
}

__global__ __launch_bounds__(256) void k_scatter(const int* __restrict__ ei, const float* __restrict__ alpha,
    const int* __restrict__ offs, int* __restrict__ rk, int2* __restrict__ sidx, float* __restrict__ alphaS){
  int g = blockIdx.x * 256 + threadIdx.x;
  int i1, i2;
  if (g < EE){ i1 = ei[2*g]; i2 = ei[2*g + 1]; }
  else { int gg = g - EE; i1 = ei[2*gg + 1]; i2 = ei[2*gg]; }
  int r = atomicAdd(rk + i1, 1);
  int pos = offs[i1] + r;
  sidx[pos] = make_int2(i1, i2);
  alphaS[pos] = alpha[g];
}

__global__ __launch_bounds__(256) void k_dens(const int* __restrict__ offs, const float* __restrict__ alphaS,
                                              float* __restrict__ den){
  int n = blockIdx.x * 4 + (threadIdx.x >> 6);
  int lane = threadIdx.x & 63;
  int b = offs[n], e = offs[n + 1];
  float s = 0.f;
  for (int i = b + lane; i < e; i += 64) s += alphaS[i];
  #pragma unroll
  for (int st = 1; st < 64; st <<= 1) s += __shfl_xor(s, st);
  if (lane == 0) den[n] = s + (n == 0 ? 2048.f : 0.f);
}

// ---------------- MFMA tile helpers ----------------
template<int NT, int KS, int SR>
__device__ __forceinline__ void tile_gemm(const char* sm, int aBase, int bBase, int lane, f32x4* acc){
  const int r15 = lane & 15;
  const int kb = (lane >> 4) * 16;
  #pragma unroll
  for (int ks = 0; ks < KS; ks++){
    bf16x8 a = *(const bf16x8*)(sm + aBase + swzb(r15*SR + ks*64 + kb, r15));
    #pragma unroll
    for (int ct = 0; ct < NT; ct++){
      int n = ct*16 + r15;
      bf16x8 b = *(const bf16x8*)(sm + bBase + swzb(n*SR + ks*64 + kb, n));
      acc[ct] = __builtin_amdgcn_mfma_f32_16x16x32_bf16(a, b, acc[ct], 0, 0, 0);
    }
  }
}

// B directly from global (L2-hot weight pool), un-swizzled [Nc][Kp] bf16
template<int NT, int KS, int SR>
__device__ __forceinline__ void tile_gemm_gb(const char* sm, int aBase, const u16* __restrict__ W, int Kp,
                                             int lane, f32x4* acc){
  const int r15 = lane & 15;
  const int kb = (lane >> 4) * 16;
  const int ke = (lane >> 4) * 8;
  #pragma unroll
  for (int ks = 0; ks < KS; ks++){
    bf16x8 a = *(const bf16x8*)(sm + aBase + swzb(r15*SR + ks*64 + kb, r15));
    #pragma unroll
    for (int ct = 0; ct < NT; ct++){
      int n = ct*16 + r15;
      bf16x8 b = *(const bf16x8*)(W + n*Kp + ks*32 + ke);
      acc[ct] = __builtin_amdgcn_mfma_f32_16x16x32_bf16(a, b, acc[ct], 0, 0, 0);
    }
  }
}

// ---------------- generic GEMM: C[M][Nc] = act(A[M][K] @ W + bias), M mult of 64 ----------------
// PACK=1: Nc must be 288; cols [0,96) -> C (stride 288), cols [96,288) -> packed kvp[h][row][16]
template<int NT, int KS, int ACT, int PACK = 0>
__global__ __launch_bounds__(256) void k_gemm(const float* __restrict__ A, int K,
    const u16* __restrict__ Wt, const float* __restrict__ bias, float* __restrict__ C,
    float* __restrict__ C2)
{
  constexpr int Kpad = KS * 32;
  constexpr int Nc = NT * 16;
  constexpr int SR = (Kpad*2 + 127) / 128 * 128;
  constexpr int ABASE = Nc * SR;
  __shared__ __align__(16) char smem[Nc*SR + 64*SR];
  constexpr int KP8 = Kpad / 8;
  for (int j = threadIdx.x; j < Nc*KP8; j += 256){
    int n = j / KP8;
    *(uint4*)(smem + swzb(n*SR + (j - n*KP8)*16, n)) = ((const uint4*)Wt)[j];
  }
  const int row0 = blockIdx.x * 64;
  for (int j = threadIdx.x; j < 64*(Kpad/2); j += 256){
    int r = j / (Kpad/2); int c = (j - r*(Kpad/2)) * 2;
    const float* ap = A + (size_t)(row0 + r)*K + c;
    float f0 = (c < K) ? ap[0] : 0.f;
    float f1 = (c + 1 < K) ? ap[1] : 0.f;
    *(u32*)(smem + ABASE + swzb(r*SR + c*2, r)) = (u32)f2bf(f0) | ((u32)f2bf(f1) << 16);
  }
  __syncthreads();
  const int lane = threadIdx.x & 63, w = threadIdx.x >> 6;
  const int r15 = lane & 15;
  f32x4 acc[NT] = {};
  tile_gemm<NT, KS, SR>(smem, ABASE + w*16*SR, 0, lane, acc);
  #pragma unroll
  for (int ct = 0; ct < NT; ct++){
    int col = ct*16 + r15;
    float bs = bias ? bias[col] : 0.f;
    #pragma unroll
    for (int q = 0; q < 4; q++){
      int r = row0 + w*16 + (lane >> 4)*4 + q;
      float v = acc[ct][q] + bs;
      if (ACT == 1) v = lrelu(v);
      if (ACT == 2) v = v > 0.f ? v : 0.f;
      if (PACK == 0){
        C[(size_t)r*Nc + col] = v;
      } else {
        if (col < 96){
          C[(size_t)r*288 + col] = v;
        } else if (col < 192){
          int hh = (col - 96) >> 3, c = (col - 96) & 7;
          C2[(((size_t)hh*2048 + r) << 4) + c] = v;
        } else {
          int hh = (col - 192) >> 3, c = (col - 192) & 7;
          C2[(((size_t)hh*2048 + r) << 4) + 8 + c] = v;
        }
      }
    }
  }
}

// ---------------- LayerNorm(a+b) ----------------
__global__ __launch_bounds__(256) void k_ln(const float* __restrict__ A, const float* __restrict__ B,
    const float* __restrict__ sc, const float* __restrict__ bi, float* __restrict__ out)
{
  const int row = blockIdx.x*4 + (threadIdx.x >> 6);
  const int lane = threadIdx.x & 63;
  const float* ap = A + row*96; const float* bp = B + row*96;
  float v1 = ap[lane] + bp[lane];
  float v2 = (lane < 32) ? (ap[64+lane] + bp[64+lane]) : 0.f;
  float sum = v1 + v2, sq = v1*v1 + v2*v2;
  #pragma unroll
  for (int st = 1; st < 64; st <<= 1){ sum += __shfl_xor(sum, st); sq += __shfl_xor(sq, st); }
  float mean = sum * (1.f/96.f);
  float var = sq * (1.f/96.f) - mean*mean;
  float rs = rsqrtf(var + 1e-5f);
  out[row*96 + lane] = (v1 - mean)*rs*sc[lane] + bi[lane];
  if (lane < 32) out[row*96 + 64 + lane] = (v2 - mean)*rs*sc[64+lane] + bi[64+lane];
}

// ---------------- attention v4: one block owns (head, 64 rows), 16 waves split keys, LDS combine ----
__global__ __launch_bounds__(1024) void k_attn4(const float* __restrict__ qkv, const float* __restrict__ kvp,
                                                float* __restrict__ obuf){
  __shared__ float part[16][64][11];
  __shared__ float red[64][10];
  const int tid = threadIdx.x;
  const int lane = tid & 63, w = tid >> 6;
  const int head = blockIdx.x >> 5, rb = blockIdx.x & 31;
  const int row = rb*64 + lane;
  const float* qp = qkv + (size_t)row*288 + head*8;
  float4 qa = *(const float4*)qp;
  float4 qb = *(const float4*)(qp + 4);
  const float* kv = kvp + ((size_t)head*2048 + w*128)*16;
  float sm = 0.f;
  float o0=0,o1=0,o2=0,o3=0,o4=0,o5=0,o6=0,o7=0;
  #pragma unroll 4
  for (int j = 0; j < 128; j++){
    const float* kp = kv + j*16;
    float4 ka = *(const float4*)kp;
    float4 kb = *(const float4*)(kp + 4);
    float4 va = *(const float4*)(kp + 8);
    float4 vb = *(const float4*)(kp + 12);
    float s = qa.x*ka.x + qa.y*ka.y + qa.z*ka.z + qa.w*ka.w
            + qb.x*kb.x + qb.y*kb.y + qb.z*kb.z + qb.w*kb.w;
    s = fminf(s * 0.35355339059327373f, 60.f);
    float p = __expf(s);
    sm += p;
    o0 += p*va.x; o1 += p*va.y; o2 += p*va.z; o3 += p*va.w;
    o4 += p*vb.x; o5 += p*vb.y; o6 += p*vb.z; o7 += p*vb.w;
  }
  float* pp = part[w][lane];
  pp[0]=o0; pp[1]=o1; pp[2]=o2; pp[3]=o3; pp[4]=o4; pp[5]=o5; pp[6]=o6; pp[7]=o7; pp[8]=sm;
  __syncthreads();
  if (tid < 576){
    int r = tid / 9, d = tid - 9*r;
    float s = 0.f;
    #pragma unroll
    for (int w2 = 0; w2 < 16; w2++) s += part[w2][r][d];
    red[r][d] = s;
  }
  __syncthreads();
  if (tid < 512){
    int r = tid >> 3, d = tid & 7;
    obuf[(size_t)(rb*64 + r)*96 + head*8 + d] = red[r][d] / red[r][8];
  }
}

// ---------------- fused edge MLPs: ef -> ein1 -> ein2 (efnn) -> {ad, ar} -> alpha ----------------
__global__ __launch_bounds__(256) void k_edge(const float* __restrict__ efr, const float* __restrict__ es,
    const u16* __restrict__ pool,
    const float* __restrict__ eb1, const float* __restrict__ eb2,
    const float* __restrict__ adb1, const float* __restrict__ adw2, const float* __restrict__ adb2,
    const float* __restrict__ arb1, const float* __restrict__ arw2, const float* __restrict__ arb2,
    u16* __restrict__ efnn, float* __restrict__ alpha)
{
  __shared__ __align__(16) char smem[49152];
  const int tid = threadIdx.x;
  const int e0 = blockIdx.x * 64;
  for (int j = tid; j < 256; j += 256){
    int n = j >> 2;
    *(uint4*)(smem + swzb(n*128 + (j&3)*16, n)) = ((const uint4*)(pool + EIN1T))[j];
  }
  for (int j = tid; j < 512; j += 256){
    int n = j >> 3; int b = n*128 + (j&7)*16;
    *(uint4*)(smem + 8192  + swzb(b, n)) = ((const uint4*)(pool + EIN2T))[j];
    *(uint4*)(smem + 16384 + swzb(b, n)) = ((const uint4*)(pool + AD1T))[j];
    *(uint4*)(smem + 24576 + swzb(b, n)) = ((const uint4*)(pool + AR1T))[j];
  }
  for (int j = tid; j < 64*16; j += 256){
    int r = j >> 4; int c = (j & 15) * 2;
    float f0 = 0.f, f1 = 0.f;
    if (c < 12)     f0 = (efr[(e0+r)*12 + c]     + 1e-4f) / es[c];
    if (c + 1 < 12) f1 = (efr[(e0+r)*12 + c + 1] + 1e-4f) / es[c+1];
    *(u32*)(smem + 32768 + swzb(r*128 + c*2, r)) = (u32)f2bf(f0) | ((u32)f2bf(f1) << 16);
  }
  __syncthreads();
  const int lane = tid & 63, w = tid >> 6;
  const int r15 = lane & 15;

  auto store_lds = [&](f32x4* acc, int base, const float* bias){
    #pragma unroll
    for (int ct = 0; ct < 4; ct++){
      int col = ct*16 + r15;
      float bs = bias[col];
      #pragma unroll
      for (int q = 0; q < 4; q++){
        int row = w*16 + (lane >> 4)*4 + q;
        *(u16*)(smem + base + swzb(row*128 + col*2, row)) = f2bf(lrelu(acc[ct][q] + bs));
      }
    }
  };

  { f32x4 acc[4] = {};
    tile_gemm<4,1,128>(smem, 32768 + w*2048, 0, lane, acc);
    store_lds(acc, 40960, eb1); }
  { f32x4 acc[4] = {};
    tile_gemm<4,2,128>(smem, 40960 + w*2048, 8192, lane, acc);
    store_lds(acc, 32768, eb2); }
  __syncthreads();
  for (int j = tid; j < 2048; j += 256){
    int r = j >> 5;
    ((u32*)efnn)[e0*32 + j] = *(const u32*)(smem + 32768 + swzb(r*128 + (j&31)*4, r));
  }
  { f32x4 acc[4] = {};
    tile_gemm<4,2,128>(smem, 32768 + w*2048, 16384, lane, acc);
    store_lds(acc, 40960, adb1); }
  __syncthreads();
  { int row = tid >> 2, part = tid & 3;
    float s = 0.f;
    #pragma unroll
    for (int i = 0; i < 16; i++){
      int k = part*16 + i;
      s += bf2f(*(const u16*)(smem + 40960 + swzb(row*128 + k*2, row))) * adw2[k];
    }
    s += __shfl_xor(s, 1); s += __shfl_xor(s, 2);
    if (part == 0) alpha[e0 + row] = 1.f / (1.f + __expf(-(s + adb2[0]))); }
  __syncthreads();
  { f32x4 acc[4] = {};
    tile_gemm<4,2,128>(smem, 32768 + w*2048, 24576, lane, acc);
    store_lds(acc, 40960, arb1); }
  __syncthreads();
  { int row = tid >> 2, part = tid & 3;
    float s = 0.f;
    #pragma unroll
    for (int i = 0; i < 16; i++){
      int k = part*16 + i;
      s += bf2f(*(const u16*)(smem + 40960 + swzb(row*128 + k*2, row))) * arw2[k];
    }
    s += __shfl_xor(s, 1); s += __shfl_xor(s, 2);
    if (part == 0) alpha[EE + e0 + row] = 1.f / (1.f + __expf(-(s + arb2[0]))); }
}

// ---------------- graph-conv v3: h1 = lrelu(P1[i1]+P2[i2]) -> GEMM2 -> segment scan ----------------
__global__ __launch_bounds__(256) void k_gc3(const float* __restrict__ P1, const float* __restrict__ P2,
    const int2* __restrict__ sidx, const float* __restrict__ alphaS, const u16* __restrict__ wt2,
    const float* __restrict__ b2, float* __restrict__ num)
{
  __shared__ __align__(16) char smem[51712];
  int*   nid  = (int*)(smem + 50176);
  int*   i2s  = (int*)(smem + 50688);
  float* alph = (float*)(smem + 51200);
  const int tid = threadIdx.x;
  const int row0 = blockIdx.x * 128;
  if (tid < 128){
    int2 p = sidx[row0 + tid];
    nid[tid] = p.x; i2s[tid] = p.y;
    alph[tid] = alphaS[row0 + tid];
  }
  __syncthreads();
  for (int j = tid; j < 128*24; j += 256){
    int r = j / 24, q = j - (j/24)*24;
    int c8 = q * 8;
    const float* p1 = P1 + (size_t)nid[r]*192 + c8;
    const float* p2 = P2 + (size_t)i2s[r]*192 + c8;
    float4 a0 = *(const float4*)p1, a1 = *(const float4*)(p1 + 4);
    float4 b0 = *(const float4*)p2, b1 = *(const float4*)(p2 + 4);
    u16 pk[8];
    pk[0]=f2bf(lrelu(a0.x+b0.x)); pk[1]=f2bf(lrelu(a0.y+b0.y));
    pk[2]=f2bf(lrelu(a0.z+b0.z)); pk[3]=f2bf(lrelu(a0.w+b0.w));
    pk[4]=f2bf(lrelu(a1.x+b1.x)); pk[5]=f2bf(lrelu(a1.y+b1.y));
    pk[6]=f2bf(lrelu(a1.z+b1.z)); pk[7]=f2bf(lrelu(a1.w+b1.w));
    *(bf16x8*)(smem + swzb(r*384 + c8*2, r)) = *(bf16x8*)pk;
  }
  __syncthreads();
  const int lane = tid & 63, w = tid >> 6;
  const int wr = w >> 1, wc = w & 1;
  const int r15 = lane & 15;
  const int kb = (lane >> 4) * 16;
  const int ke = (lane >> 4) * 8;
  f32x4 acc2[4][3] = {};
  #pragma unroll
  for (int ks = 0; ks < 6; ks++){
    bf16x8 a[4];
    #pragma unroll
    for (int rt = 0; rt < 4; rt++){
      int row = wr*64 + rt*16 + r15;
      a[rt] = *(const bf16x8*)(smem + swzb(row*384 + ks*64 + kb, row));
    }
    #pragma unroll
    for (int ct = 0; ct < 3; ct++){
      int n = wc*48 + ct*16 + r15;
      bf16x8 b = *(const bf16x8*)(wt2 + n*192 + ks*32 + ke);
      #pragma unroll
      for (int rt = 0; rt < 4; rt++)
        acc2[rt][ct] = __builtin_amdgcn_mfma_f32_16x16x32_bf16(a[rt], b, acc2[rt][ct], 0, 0, 0);
    }
  }
  __syncthreads();
  #pragma unroll
  for (int ct = 0; ct < 3; ct++){
    int col = wc*48 + ct*16 + r15;
    float bs = b2[col];
    #pragma unroll
    for (int rt = 0; rt < 4; rt++){
      #pragma unroll
      for (int q = 0; q < 4; q++){
        int row = wr*64 + rt*16 + (lane >> 4)*4 + q;
        *(float*)(smem + row*392 + col*4) = alph[row] * lrelu(acc2[rt][ct][q] + bs);
      }
    }
  }
  __syncthreads();
  if (tid < 192){
    int hf = tid / 96;
    int c = tid - hf*96;
    int rbeg = hf*64, rend = rbeg + 64;
    float accv = 0.f;
    int cur = nid[rbeg];
    for (int r = rbeg; r < rend; r++){
      int n2 = nid[r];
      if (n2 != cur){ atomicAdd(num + cur*96 + c, accv); accv = 0.f; cur = n2; }
      accv += *(const float*)(smem + r*392 + c*4);
    }
    atomicAdd(num + cur*96 + c, accv);
  }
}

// the N rows with ind1=ind2=0 are identical: compute once, add 2048x
__global__ __launch_bounds__(256) void k_gcnode0(const float* __restrict__ h,
    const float* __restrict__ W1, const float* __restrict__ b1,
    const float* __restrict__ W2, const float* __restrict__ b2, float* __restrict__ num)
{
  __shared__ float in_s[192], h1_s[192];
  int t = threadIdx.x;
  if (t < 192) in_s[t] = h[t % 96];
  __syncthreads();
  if (t < 192){
    float s = b1[t];
    for (int k = 0; k < 192; k++) s += in_s[k] * W1[k*192 + t];
    h1_s[t] = lrelu(s);
  }
  __syncthreads();
  if (t < 96){
    float s = b2[t];
    for (int k = 0; k < 192; k++) s += h1_s[k] * W2[k*96 + t];
    num[t] += 2048.f * lrelu(s);
  }
}

__global__ __launch_bounds__(256) void k_hupd(const float* __restrict__ num, const float* __restrict__ den,
                                              float* __restrict__ h){
  int i = blockIdx.x * 256 + threadIdx.x;
  h[i] = num[i] / (den[i / 96] + 1e-8f);
}

// ---------------- final predictor v2 ----------------
__global__ __launch_bounds__(256) void k_final2(const float* __restrict__ hp1, const float* __restrict__ hp2,
    const int* __restrict__ ei, const u16* __restrict__ efnn, const float* __restrict__ efr,
    const float* __restrict__ es, const u16* __restrict__ enc,
    const float* __restrict__ enw2, const float* __restrict__ enb2, float* __restrict__ out)
{
  __shared__ __align__(16) char smem[38144];
  float* etb = (float*)(smem + 12288);
  float* w2s = (float*)(smem + 37120);
  int*   eix = (int*)  (smem + 37504);
  const int tid = threadIdx.x;
  const int e0 = blockIdx.x * 64;
  for (int j = tid; j < 768; j += 256){
    int r = j / 12, q = j - (j/12)*12;
    int e = e0 + r;
    bf16x8 v;
    if (q < 8){
      v = *(const bf16x8*)(efnn + (size_t)e*64 + q*8);
    } else if (q < 10){
      u16 pk[8];
      #pragma unroll
      for (int i = 0; i < 8; i++){
        int cc = (q - 8)*8 + i;
        pk[i] = (cc < 12) ? f2bf((efr[(size_t)e*12 + cc] + 1e-4f) / es[cc]) : (u16)0;
      }
      v = *(bf16x8*)pk;
    } else {
      v = bf16x8{0,0,0,0,0,0,0,0};
    }
    *(bf16x8*)(smem + swzb(r*192 + q*16, r)) = v;
  }
  if (tid < 96) w2s[tid] = enw2[tid];
  if (tid < 64){ eix[2*tid] = ei[2*(e0+tid)]; eix[2*tid+1] = ei[2*(e0+tid)+1]; }
  __syncthreads();
  const int lane = tid & 63, w = tid >> 6;
  const int r15 = lane & 15;
  f32x4 acc[6] = {};
  tile_gemm_gb<6,3,192>(smem, w*16*192, enc, 96, lane, acc);
  #pragma unroll
  for (int ct = 0; ct < 6; ct++){
    int col = ct*16 + r15;
    #pragma unroll
    for (int q = 0; q < 4; q++){
      int row = w*16 + (lane >> 4)*4 + q;
      etb[row*97 + col] = acc[ct][q];
    }
  }
  __syncthreads();
  int r = tid >> 2, part = tid & 3;
  int s1 = eix[2*r], s2 = eix[2*r + 1];
  const float* p1 = hp1 + (size_t)s1*96 + part*24;
  const float* p2 = hp2 + (size_t)s2*96 + part*24;
  const float* et = etb + r*97 + part*24;
  const float* wz = w2s + part*24;
  float s = 0.f;
  #pragma unroll
  for (int i = 0; i < 24; i++){
    float v = et[i] + p1[i] + p2[i];
    s += lrelu(v) * wz[i];
  }
  s += __shfl_xor(s, 1); s += __shfl_xor(s, 2);
  if (part == 0) out[e0 + r] = 1.f / (1.f + __expf(-(s + enb2[0])));
}

// ---------------- host ----------------
extern "C" void kernel_launch(void* const* d_in, const int* in_sizes, int n_in,
                              void* d_out, int out_size, void* d_ws, size_t ws_size,
                              hipStream_t stream) {
  (void)in_sizes; (void)n_in; (void)out_size; (void)ws_size;
  const float* X      = (const float*)d_in[0];
  const float* EFR    = (const float*)d_in[1];
  const int*   EI     = (const int*)  d_in[2];
  const float* NS     = (const float*)d_in[3];
  const float* ES     = (const float*)d_in[4];
  const float* IN_W1  = (const float*)d_in[5];
  const float* IN_B1  = (const float*)d_in[6];
  const float* IN_W2  = (const float*)d_in[7];
  const float* IN_B2  = (const float*)d_in[8];
  const float* QKV_W  = (const float*)d_in[9];
  const float* QKV_B  = (const float*)d_in[10];
  const float* OUT_W  = (const float*)d_in[11];
  const float* OUT_B  = (const float*)d_in[12];
  const float* LN1S   = (const float*)d_in[13];
  const float* LN1B   = (const float*)d_in[14];
  const float* FFW1   = (const float*)d_in[15];
  const float* FFB1   = (const float*)d_in[16];
  const float* FFW2   = (const float*)d_in[17];
  const float* FFB2   = (const float*)d_in[18];
  const float* LN2S   = (const float*)d_in[19];
  const float* LN2B   = (const float*)d_in[20];
  const float* EIN_W1 = (const float*)d_in[21];
  const float* EIN_B1 = (const float*)d_in[22];
  const float* EIN_W2 = (const float*)d_in[23];
  const float* EIN_B2 = (const float*)d_in[24];
  const float* AD_W1  = (const float*)d_in[25];
  const float* AD_B1  = (const float*)d_in[26];
  const float* AD_W2  = (const float*)d_in[27];
  const float* AD_B2  = (const float*)d_in[28];
  const float* AR_W1  = (const float*)d_in[29];
  const float* AR_B1  = (const float*)d_in[30];
  const float* AR_W2  = (const float*)d_in[31];
  const float* AR_B2  = (const float*)d_in[32];
  const float* GC_W1  = (const float*)d_in[33];
  const float* GC_B1  = (const float*)d_in[34];
  const float* GC_W2  = (const float*)d_in[35];
  const float* GC_B2  = (const float*)d_in[36];
  const float* EN_W1  = (const float*)d_in[37];
  const float* EN_B1  = (const float*)d_in[38];
  const float* EN_W2  = (const float*)d_in[39];
  const float* EN_B2  = (const float*)d_in[40];

  char* ws = (char*)d_ws;
  u16*   pool   = (u16*)  (ws + WS_WT);
  u16*   efnn   = (u16*)  (ws + WS_EFNN);
  float* alpha  = (float*)(ws + WS_ALPHA);
  float* h      = (float*)(ws + WS_H);
  float* qkvb   = (float*)(ws + WS_QKV);
  float* obuf   = (float*)(ws + WS_OBUF);
  float* tmpA   = (float*)(ws + WS_TMPA);
  float* tmpB   = (float*)(ws + WS_TMPB);
  float* x1     = (float*)(ws + WS_X1);
  float* num    = (float*)(ws + WS_NUM);
  float* den    = (float*)(ws + WS_DEN);
  float* xs     = (float*)(ws + WS_XS);
  int2*  sidx   = (int2*) (ws + WS_SIDX);
  float* alphaS = (float*)(ws + WS_ALPS);
  int*   cnt    = (int*)  (ws + WS_CNT);
  int*   offs   = (int*)  (ws + WS_OFFS);
  float* P1     = (float*)(ws + WS_QKV);   // reuse (encoders done before gc)
  float* P2     = (float*)(ws + WS_TMPB);
  float* hp1    = (float*)(ws + WS_OBUF);
  float* hp2    = (float*)(ws + WS_TMPA);
  float* kvp    = (float*)(ws + WS_ALPHA); // reuse: alpha dead after k_scatter

  // ---- weight conversion jobs ----
  CvtJobs jb;
  int idx = 0, cum = 0;
  auto addjob = [&](const float* s, int K, int Nc, int Kp){
    jb.src[idx] = s; jb.K[idx] = K; jb.Nc[idx] = Nc; jb.Kp[idx] = Kp;
    jb.cum[idx] = cum; cum += Nc * Kp; idx++;
  };
  addjob(IN_W1, 19, 96, 32);
  addjob(IN_W2, 96, 96, 96);
  for (int l = 0; l < 3; l++) addjob(QKV_W + (size_t)l*96*288, 96, 288, 96);
  for (int l = 0; l < 3; l++) addjob(OUT_W + (size_t)l*96*96,  96, 96,  96);
  for (int l = 0; l < 3; l++) addjob(FFW1  + (size_t)l*96*192, 96, 192, 96);
  for (int l = 0; l < 3; l++) addjob(FFW2  + (size_t)l*192*96, 192, 96, 192);
  addjob(EIN_W1, 12, 64, 32);
  addjob(EIN_W2, 64, 64, 64);
  addjob(AD_W1,  64, 64, 64);
  addjob(AR_W1,  64, 64, 64);
  for (int i = 0; i < 2; i++){
    addjob(GC_W1 + (size_t)i*192*192,          96, 192, 96);
    addjob(GC_W1 + (size_t)i*192*192 + 96*192, 96, 192, 96);
  }
  for (int i = 0; i < 2; i++) addjob(GC_W2 + (size_t)i*192*96, 192, 96, 192);
  addjob(EN_W1,            96, 96, 96);
  addjob(EN_W1 + 96*96,    96, 96, 96);
  addjob(EN_W1 + 192*96,   76, 96, 96);
  jb.cum[idx] = cum;

  k_cvt<<<(POOL_TOT + 255)/256, 256, 0, stream>>>(jb, pool);

  // ---- node embedding ----
  k_xscale<<<(NN*19 + 255)/256, 256, 0, stream>>>(X, NS, xs);
  k_gemm<6,1,1><<<32, 256, 0, stream>>>(xs, 19, pool + IN1T, IN_B1, tmpA, nullptr);
  k_gemm<6,3,1><<<32, 256, 0, stream>>>(tmpA, 96, pool + IN2T, IN_B2, h, nullptr);

  // ---- edge MLPs + attention weights ----
  k_edge<<<EE/64, 256, 0, stream>>>(EFR, ES, pool, EIN_B1, EIN_B2,
                                    AD_B1, AD_W2, AD_B2, AR_B1, AR_W2, AR_B2, efnn, alpha);

  // ---- destination sort + den ----
  (void)hipMemsetAsync(cnt, 0, NN*4, stream);
  k_hist<<<(2*EE)/256, 256, 0, stream>>>(EI, cnt);
  k_scan<<<1, 256, 0, stream>>>(cnt, offs);
  (void)hipMemsetAsync(cnt, 0, NN*4, stream);
  k_scatter<<<(2*EE)/256, 256, 0, stream>>>(EI, alpha, offs, cnt, sidx, alphaS);
  k_dens<<<NN/4, 256, 0, stream>>>(offs, alphaS, den);

  // ---- 3 encoder layers ----
  for (int l = 0; l < 3; l++){
    k_gemm<18,3,0,1><<<32, 256, 0, stream>>>(h, 96, pool + QKVT + l*27648, QKV_B + l*288, qkvb, kvp);
    k_attn4<<<384, 1024, 0, stream>>>(qkvb, kvp, obuf);
    k_gemm<6,3,0><<<32, 256, 0, stream>>>(obuf, 96, pool + OUTT + l*9216, OUT_B + l*96, tmpA, nullptr);
    k_ln<<<512, 256, 0, stream>>>(h, tmpA, LN1S + l*96, LN1B + l*96, x1);
    k_gemm<12,3,2><<<32, 256, 0, stream>>>(x1, 96, pool + FF1T + l*18432, FFB1 + l*192, tmpB, nullptr);
    k_gemm<6,6,0><<<32, 256, 0, stream>>>(tmpB, 192, pool + FF2T + l*18432, FFB2 + l*96, tmpA, nullptr);
    k_ln<<<512, 256, 0, stream>>>(x1, tmpA, LN2S + l*96, LN2B + l*96, h);
  }

  // ---- 2 graph-conv iterations ----
  for (int it = 0; it < 2; it++){
    k_gemm<12,3,0><<<32, 256, 0, stream>>>(h, 96, pool + GC1T + it*36864,         nullptr,        P1, nullptr);
    k_gemm<12,3,0><<<32, 256, 0, stream>>>(h, 96, pool + GC1T + it*36864 + 18432, GC_B1 + it*192, P2, nullptr);
    (void)hipMemsetAsync(num, 0, NN*96*4, stream);
    k_gc3<<<(2*EE)/128, 256, 0, stream>>>(P1, P2, sidx, alphaS,
        pool + GC2T + it*18432, GC_B2 + it*96, num);
    k_gcnode0<<<1, 256, 0, stream>>>(h, GC_W1 + (size_t)it*192*192, GC_B1 + it*192,
                                     GC_W2 + (size_t)it*192*96, GC_B2 + it*96, num);
    k_hupd<<<(NN*96)/256, 256, 0, stream>>>(num, den, h);
  }

  // ---- final predictor ----
  k_gemm<6,3,0><<<32, 256, 0, stream>>>(h, 96, pool + ENAT, nullptr, hp1, nullptr);
  k_gemm<6,3,0><<<32, 256, 0, stream>>>(h, 96, pool + ENBT, EN_B1, hp2, nullptr);
  k_final2<<<EE/64, 256, 0, stream>>>(hp1, hp2, EI, efnn, EFR, ES,
                                      pool + ENCT, EN_W2, EN_B2, (float*)d_out);
}

// Round 7
// 805.643 us; speedup vs baseline: 1.2982x; 1.2818x over previous
//
#include <hip/hip_runtime.h>

// ---------------- constants ----------------
#define NN 2048
#define EE 262144

typedef __attribute__((ext_vector_type(8))) short bf16x8;
typedef __attribute__((ext_vector_type(4))) float f32x4;
typedef unsigned int u32;
typedef unsigned short u16;

__device__ __forceinline__ u16 f2bf(float f){
  u32 u = __builtin_bit_cast(u32, f);
  u32 r = u + 0x7FFFu + ((u >> 16) & 1u);
  return (u16)(r >> 16);
}
__device__ __forceinline__ float bf2f(u16 h){
  u32 u = ((u32)h) << 16;
  return __builtin_bit_cast(float, u);
}
__device__ __forceinline__ int swzb(int byte, int row){ return byte ^ ((row & 7) << 4); }
__device__ __forceinline__ float lrelu(float v){ return v > 0.f ? v : 0.01f * v; }

// ---------------- ws layout (bytes) ----------------
static const size_t WS_WT    = 0;                    // u16 pool (772096 B)
static const size_t WS_EFNN  = 772096;               // u16 E*64
static const size_t WS_ALPHA = WS_EFNN  + 33554432;  // f32 2E ; kvp reuses this after sort
static const size_t WS_H     = WS_ALPHA + 2097152;   // f32 N*96
static const size_t WS_QKV   = WS_H     + 786432;    // f32 N*288 ; P1 reuses this
static const size_t WS_OBUF  = WS_QKV   + 2359296;   // f32 N*96  ; hp1 reuses this
static const size_t WS_TMPA  = WS_OBUF  + 786432;    // f32 N*96  ; hp2 reuses this
static const size_t WS_TMPB  = WS_TMPA  + 786432;    // f32 N*192 ; P2 reuses this
static const size_t WS_X1    = WS_TMPB  + 1572864;   // f32 N*96
static const size_t WS_NUM   = WS_X1    + 786432;    // f32 N*96
static const size_t WS_DEN   = WS_NUM   + 786432;    // f32 N (pad)
static const size_t WS_XS    = WS_DEN   + 8192;      // f32 N*19 (pad)
static const size_t WS_HBF   = WS_XS    + 155648;    // (dead)
static const size_t WS_SIDX  = WS_HBF   + 393216;    // int2 2E
static const size_t WS_ALPS  = WS_SIDX  + 4194304;   // f32 2E (sorted alpha)
static const size_t WS_CNT   = WS_ALPS  + 2097152;   // int N
static const size_t WS_OFFS  = WS_CNT   + 8192;      // int N+1 (pad)

// pool element offsets (bf16, weights transposed [Nc][Kpad])
#define IN1T 0
#define IN2T 3072
#define QKVT 12288
#define OUTT 95232
#define FF1T 122880
#define FF2T 178176
#define EIN1T 233472
#define EIN2T 235520
#define AD1T 239616
#define AR1T 243712
#define GC1T 247808
#define GC2T 321536
#define ENAT 358400
#define ENBT 367616
#define ENCT 376832
#define POOL_TOT 386048

// ---------------- weight convert (f32 -> bf16, transposed, K-padded) ----------------
struct CvtJobs {
  const float* src[27];
  int K[27], Nc[27], Kp[27];
  int cum[28];
};

__global__ __launch_bounds__(256) void k_cvt(CvtJobs jb, u16* __restrict__ pool){
  int i = blockIdx.x * 256 + threadIdx.x;
  if (i >= jb.cum[27]) return;
  int j = 0;
  while (i >= jb.cum[j + 1]) j++;
  int loc = i - jb.cum[j];
  int Kp = jb.Kp[j];
  int n = loc / Kp, k = loc - n * Kp;
  float v = (k < jb.K[j]) ? jb.src[j][(size_t)k * jb.Nc[j] + n] : 0.f;
  pool[i] = f2bf(v);
}

__global__ __launch_bounds__(256) void k_xscale(const float* __restrict__ X, const float* __restrict__ ns,
                                                float* __restrict__ xs){
  int i = blockIdx.x * 256 + threadIdx.x;
  if (i < NN * 19) xs[i] = X[i] / ns[i % 19];
}

// ---------------- destination sort (counting sort over 2E edge rows) ----------------
__global__ __launch_bounds__(256) void k_hist(const int* __restrict__ ei, int* __restrict__ cnt){
  int g = blockIdx.x * 256 + threadIdx.x;
  int i1 = (g < EE) ? ei[2*g] : ei[2*(g - EE) + 1];
  atomicAdd(cnt + i1, 1);
}

__global__ __launch_bounds__(256) void k_scan(const int* __restrict__ cnt, int* __restrict__ offs){
  __shared__ int wsum[4], wbase[4];
  int t = threadIdx.x;
  int base = t * 8;
  int c[8]; int T = 0;
  #pragma unroll
  for (int i = 0; i < 8; i++){ c[i] = cnt[base + i]; T += c[i]; }
  int lane = t & 63, wv = t >> 6;
  int inc = T;
  #pragma unroll
  for (int st = 1; st < 64; st <<= 1){
    int v = __shfl_up(inc, st);
    if (lane >= st) inc += v;
  }
  if (lane == 63) wsum[wv] = inc;
  __syncthreads();
  if (t == 0){ int r = 0; for (int w2 = 0; w2 < 4; w2++){ wbase[w2] = r; r += wsum[w2]; } }
  __syncthreads();
  int run = wbase[wv] + inc - T;
  #pragma unroll
  for (int i = 0; i < 8; i++){ offs[base + i] = run; run += c[i]; }
  if (t == 255) offs[2048] = run;
}

__global__ __launch_bounds__(256) void k_scatter(const int* __restrict__ ei, const float* __restrict__ alpha,
    const int* __restrict__ offs, int* __restrict__ rk, int2* __restrict__ sidx, float* __restrict__ alphaS){
  int g = blockIdx.x * 256 + threadIdx.x;
  int i1, i2;
  if (g < EE){ i1 = ei[2*g]; i2 = ei[2*g + 1]; }
  else { int gg = g - EE; i1 = ei[2*gg + 1]; i2 = ei[2*gg]; }
  int r = atomicAdd(rk + i1, 1);
  int pos = offs[i1] + r;
  sidx[pos] = make_int2(i1, i2);
  alphaS[pos] = alpha[g];
}

__global__ __launch_bounds__(256) void k_dens(const int* __restrict__ offs, const float* __restrict__ alphaS,
                                              float* __restrict__ den){
  int n = blockIdx.x * 4 + (threadIdx.x >> 6);
  int lane = threadIdx.x & 63;
  int b = offs[n], e = offs[n + 1];
  float s = 0.f;
  for (int i = b + lane; i < e; i += 64) s += alphaS[i];
  #pragma unroll
  for (int st = 1; st < 64; st <<= 1) s += __shfl_xor(s, st);
  if (lane == 0) den[n] = s + (n == 0 ? 2048.f : 0.f);
}

// ---------------- MFMA tile helpers ----------------
template<int NT, int KS, int SR>
__device__ __forceinline__ void tile_gemm(const char* sm, int aBase, int bBase, int lane, f32x4* acc){
  const int r15 = lane & 15;
  const int kb = (lane >> 4) * 16;
  #pragma unroll
  for (int ks = 0; ks < KS; ks++){
    bf16x8 a = *(const bf16x8*)(sm + aBase + swzb(r15*SR + ks*64 + kb, r15));
    #pragma unroll
    for (int ct = 0; ct < NT; ct++){
      int n = ct*16 + r15;
      bf16x8 b = *(const bf16x8*)(sm + bBase + swzb(n*SR + ks*64 + kb, n));
      acc[ct] = __builtin_amdgcn_mfma_f32_16x16x32_bf16(a, b, acc[ct], 0, 0, 0);
    }
  }
}

// B directly from global (L2-hot weight pool), un-swizzled [Nc][Kp] bf16
template<int NT, int KS, int SR>
__device__ __forceinline__ void tile_gemm_gb(const char* sm, int aBase, const u16* __restrict__ W, int Kp,
                                             int lane, f32x4* acc){
  const int r15 = lane & 15;
  const int kb = (lane >> 4) * 16;
  const int ke = (lane >> 4) * 8;
  #pragma unroll
  for (int ks = 0; ks < KS; ks++){
    bf16x8 a = *(const bf16x8*)(sm + aBase + swzb(r15*SR + ks*64 + kb, r15));
    #pragma unroll
    for (int ct = 0; ct < NT; ct++){
      int n = ct*16 + r15;
      bf16x8 b = *(const bf16x8*)(W + n*Kp + ks*32 + ke);
      acc[ct] = __builtin_amdgcn_mfma_f32_16x16x32_bf16(a, b, acc[ct], 0, 0, 0);
    }
  }
}

// ---------------- generic GEMM: C[M][Nc] = act(A[M][K] @ W + bias), M mult of 64 ----------------
// PACK=1: Nc must be 288; cols [0,96) -> C (stride 288), cols [96,288) -> packed kvp[h][row][16]
template<int NT, int KS, int ACT, int PACK = 0>
__global__ __launch_bounds__(256) void k_gemm(const float* __restrict__ A, int K,
    const u16* __restrict__ Wt, const float* __restrict__ bias, float* __restrict__ C,
    float* __restrict__ C2)
{
  constexpr int Kpad = KS * 32;
  constexpr int Nc = NT * 16;
  constexpr int SR = (Kpad*2 + 127) / 128 * 128;
  constexpr int ABASE = Nc * SR;
  __shared__ __align__(16) char smem[Nc*SR + 64*SR];
  constexpr int KP8 = Kpad / 8;
  for (int j = threadIdx.x; j < Nc*KP8; j += 256){
    int n = j / KP8;
    *(uint4*)(smem + swzb(n*SR + (j - n*KP8)*16, n)) = ((const uint4*)Wt)[j];
  }
  const int row0 = blockIdx.x * 64;
  for (int j = threadIdx.x; j < 64*(Kpad/2); j += 256){
    int r = j / (Kpad/2); int c = (j - r*(Kpad/2)) * 2;
    const float* ap = A + (size_t)(row0 + r)*K + c;
    float f0 = (c < K) ? ap[0] : 0.f;
    float f1 = (c + 1 < K) ? ap[1] : 0.f;
    *(u32*)(smem + ABASE + swzb(r*SR + c*2, r)) = (u32)f2bf(f0) | ((u32)f2bf(f1) << 16);
  }
  __syncthreads();
  const int lane = threadIdx.x & 63, w = threadIdx.x >> 6;
  const int r15 = lane & 15;
  f32x4 acc[NT] = {};
  tile_gemm<NT, KS, SR>(smem, ABASE + w*16*SR, 0, lane, acc);
  #pragma unroll
  for (int ct = 0; ct < NT; ct++){
    int col = ct*16 + r15;
    float bs = bias ? bias[col] : 0.f;
    #pragma unroll
    for (int q = 0; q < 4; q++){
      int r = row0 + w*16 + (lane >> 4)*4 + q;
      float v = acc[ct][q] + bs;
      if (ACT == 1) v = lrelu(v);
      if (ACT == 2) v = v > 0.f ? v : 0.f;
      if (PACK == 0){
        C[(size_t)r*Nc + col] = v;
      } else {
        if (col < 96){
          C[(size_t)r*288 + col] = v;
        } else if (col < 192){
          int hh = (col - 96) >> 3, cc = (col - 96) & 7;
          C2[(((size_t)hh*2048 + r) << 4) + cc] = v;
        } else {
          int hh = (col - 192) >> 3, cc = (col - 192) & 7;
          C2[(((size_t)hh*2048 + r) << 4) + 8 + cc] = v;
        }
      }
    }
  }
}

// ---------------- LayerNorm(a+b) ----------------
__global__ __launch_bounds__(256) void k_ln(const float* __restrict__ A, const float* __restrict__ B,
    const float* __restrict__ sc, const float* __restrict__ bi, float* __restrict__ out)
{
  const int row = blockIdx.x*4 + (threadIdx.x >> 6);
  const int lane = threadIdx.x & 63;
  const float* ap = A + row*96; const float* bp = B + row*96;
  float v1 = ap[lane] + bp[lane];
  float v2 = (lane < 32) ? (ap[64+lane] + bp[64+lane]) : 0.f;
  float sum = v1 + v2, sq = v1*v1 + v2*v2;
  #pragma unroll
  for (int st = 1; st < 64; st <<= 1){ sum += __shfl_xor(sum, st); sq += __shfl_xor(sq, st); }
  float mean = sum * (1.f/96.f);
  float var = sq * (1.f/96.f) - mean*mean;
  float rs = rsqrtf(var + 1e-5f);
  out[row*96 + lane] = (v1 - mean)*rs*sc[lane] + bi[lane];
  if (lane < 32) out[row*96 + 64 + lane] = (v2 - mean)*rs*sc[64+lane] + bi[64+lane];
}

// ---------------- attention v5: (head, 16-row) blocks, LDS-staged keys, shuffle+LDS combine ----------
// kvp[h][j][16] = {K[8], V[8]} f32. Block: 256 thr; lane = (r=lane&15, q=lane>>4); wave w of 4.
// Superchunk = 256 keys (16 KB) double-buffered; (w,q) slot processes keys w*64 + i*4 + q.
__global__ __launch_bounds__(256) void k_attn5(const float* __restrict__ qkv, const float* __restrict__ kvp,
                                               float* __restrict__ obuf){
  __shared__ float kbuf[2][4096];      // 2 x 256 keys x 16
  __shared__ float part[4][16][12];
  const int tid = threadIdx.x;
  const int lane = tid & 63, w = tid >> 6;
  const int r = lane & 15, q = lane >> 4;
  const int head = blockIdx.x >> 7, rb = blockIdx.x & 127;
  const int row = rb*16 + r;
  const float* qp = qkv + (size_t)row*288 + head*8;
  float4 qa = *(const float4*)qp;
  float4 qb = *(const float4*)(qp + 4);
  const float* base = kvp + (size_t)head*32768;
  float4 st0 = *(const float4*)(base + tid*4);
  float4 st1 = *(const float4*)(base + 1024 + tid*4);
  float4 st2 = *(const float4*)(base + 2048 + tid*4);
  float4 st3 = *(const float4*)(base + 3072 + tid*4);
  *(float4*)&kbuf[0][tid*4]        = st0;
  *(float4*)&kbuf[0][1024 + tid*4] = st1;
  *(float4*)&kbuf[0][2048 + tid*4] = st2;
  *(float4*)&kbuf[0][3072 + tid*4] = st3;
  __syncthreads();
  float sm = 0.f;
  float o0=0,o1=0,o2=0,o3=0,o4=0,o5=0,o6=0,o7=0;
  for (int c = 0; c < 8; c++){
    if (c < 7){
      const float* nb = base + (c+1)*4096;
      st0 = *(const float4*)(nb + tid*4);
      st1 = *(const float4*)(nb + 1024 + tid*4);
      st2 = *(const float4*)(nb + 2048 + tid*4);
      st3 = *(const float4*)(nb + 3072 + tid*4);
    }
    const float* kp0 = &kbuf[c & 1][(w*64 + q)*16];
    #pragma unroll
    for (int i = 0; i < 16; i++){
      const float* kp = kp0 + i*64;                    // key = w*64 + i*4 + q
      float4 ka = *(const float4*)kp;
      float4 kb4 = *(const float4*)(kp + 4);
      float4 va = *(const float4*)(kp + 8);
      float4 vb = *(const float4*)(kp + 12);
      float s = qa.x*ka.x + qa.y*ka.y + qa.z*ka.z + qa.w*ka.w
              + qb.x*kb4.x + qb.y*kb4.y + qb.z*kb4.z + qb.w*kb4.w;
      s = fminf(s * 0.35355339059327373f, 60.f);
      float p = __expf(s);
      sm += p;
      o0 += p*va.x; o1 += p*va.y; o2 += p*va.z; o3 += p*va.w;
      o4 += p*vb.x; o5 += p*vb.y; o6 += p*vb.z; o7 += p*vb.w;
    }
    if (c < 7){
      float* wb = kbuf[(c+1) & 1];
      *(float4*)&wb[tid*4]        = st0;
      *(float4*)&wb[1024 + tid*4] = st1;
      *(float4*)&wb[2048 + tid*4] = st2;
      *(float4*)&wb[3072 + tid*4] = st3;
      __syncthreads();
    }
  }
  // reduce over keyslots q (lanes xor 16, 32)
  #pragma unroll
  for (int stx = 16; stx < 64; stx <<= 1){
    o0 += __shfl_xor(o0, stx); o1 += __shfl_xor(o1, stx);
    o2 += __shfl_xor(o2, stx); o3 += __shfl_xor(o3, stx);
    o4 += __shfl_xor(o4, stx); o5 += __shfl_xor(o5, stx);
    o6 += __shfl_xor(o6, stx); o7 += __shfl_xor(o7, stx);
    sm += __shfl_xor(sm, stx);
  }
  if (q == 0){
    float* pp = part[w][r];
    pp[0]=o0; pp[1]=o1; pp[2]=o2; pp[3]=o3; pp[4]=o4; pp[5]=o5; pp[6]=o6; pp[7]=o7; pp[8]=sm;
  }
  __syncthreads();
  if (tid < 128){
    int rr = tid >> 3, d = tid & 7;
    float o  = part[0][rr][d] + part[1][rr][d] + part[2][rr][d] + part[3][rr][d];
    float ss = part[0][rr][8] + part[1][rr][8] + part[2][rr][8] + part[3][rr][8];
    obuf[(size_t)(rb*16 + rr)*96 + head*8 + d] = o / ss;
  }
}

// ---------------- fused edge MLPs: ef -> ein1 -> ein2 (efnn) -> {ad, ar} -> alpha ----------------
__global__ __launch_bounds__(256) void k_edge(const float* __restrict__ efr, const float* __restrict__ es,
    const u16* __restrict__ pool,
    const float* __restrict__ eb1, const float* __restrict__ eb2,
    const float* __restrict__ adb1, const float* __restrict__ adw2, const float* __restrict__ adb2,
    const float* __restrict__ arb1, const float* __restrict__ arw2, const float* __restrict__ arb2,
    u16* __restrict__ efnn, float* __restrict__ alpha)
{
  __shared__ __align__(16) char smem[49152];
  const int tid = threadIdx.x;
  const int e0 = blockIdx.x * 64;
  for (int j = tid; j < 256; j += 256){
    int n = j >> 2;
    *(uint4*)(smem + swzb(n*128 + (j&3)*16, n)) = ((const uint4*)(pool + EIN1T))[j];
  }
  for (int j = tid; j < 512; j += 256){
    int n = j >> 3; int b = n*128 + (j&7)*16;
    *(uint4*)(smem + 8192  + swzb(b, n)) = ((const uint4*)(pool + EIN2T))[j];
    *(uint4*)(smem + 16384 + swzb(b, n)) = ((const uint4*)(pool + AD1T))[j];
    *(uint4*)(smem + 24576 + swzb(b, n)) = ((const uint4*)(pool + AR1T))[j];
  }
  for (int j = tid; j < 64*16; j += 256){
    int r = j >> 4; int c = (j & 15) * 2;
    float f0 = 0.f, f1 = 0.f;
    if (c < 12)     f0 = (efr[(e0+r)*12 + c]     + 1e-4f) / es[c];
    if (c + 1 < 12) f1 = (efr[(e0+r)*12 + c + 1] + 1e-4f) / es[c+1];
    *(u32*)(smem + 32768 + swzb(r*128 + c*2, r)) = (u32)f2bf(f0) | ((u32)f2bf(f1) << 16);
  }
  __syncthreads();
  const int lane = tid & 63, w = tid >> 6;
  const int r15 = lane & 15;

  auto store_lds = [&](f32x4* acc, int base, const float* bias){
    #pragma unroll
    for (int ct = 0; ct < 4; ct++){
      int col = ct*16 + r15;
      float bs = bias[col];
      #pragma unroll
      for (int q = 0; q < 4; q++){
        int row = w*16 + (lane >> 4)*4 + q;
        *(u16*)(smem + base + swzb(row*128 + col*2, row)) = f2bf(lrelu(acc[ct][q] + bs));
      }
    }
  };

  { f32x4 acc[4] = {};
    tile_gemm<4,1,128>(smem, 32768 + w*2048, 0, lane, acc);
    store_lds(acc, 40960, eb1); }
  { f32x4 acc[4] = {};
    tile_gemm<4,2,128>(smem, 40960 + w*2048, 8192, lane, acc);
    store_lds(acc, 32768, eb2); }
  __syncthreads();
  for (int j = tid; j < 2048; j += 256){
    int r = j >> 5;
    ((u32*)efnn)[e0*32 + j] = *(const u32*)(smem + 32768 + swzb(r*128 + (j&31)*4, r));
  }
  { f32x4 acc[4] = {};
    tile_gemm<4,2,128>(smem, 32768 + w*2048, 16384, lane, acc);
    store_lds(acc, 40960, adb1); }
  __syncthreads();
  { int row = tid >> 2, part = tid & 3;
    float s = 0.f;
    #pragma unroll
    for (int i = 0; i < 16; i++){
      int k = part*16 + i;
      s += bf2f(*(const u16*)(smem + 40960 + swzb(row*128 + k*2, row))) * adw2[k];
    }
    s += __shfl_xor(s, 1); s += __shfl_xor(s, 2);
    if (part == 0) alpha[e0 + row] = 1.f / (1.f + __expf(-(s + adb2[0]))); }
  __syncthreads();
  { f32x4 acc[4] = {};
    tile_gemm<4,2,128>(smem, 32768 + w*2048, 24576, lane, acc);
    store_lds(acc, 40960, arb1); }
  __syncthreads();
  { int row = tid >> 2, part = tid & 3;
    float s = 0.f;
    #pragma unroll
    for (int i = 0; i < 16; i++){
      int k = part*16 + i;
      s += bf2f(*(const u16*)(smem + 40960 + swzb(row*128 + k*2, row))) * arw2[k];
    }
    s += __shfl_xor(s, 1); s += __shfl_xor(s, 2);
    if (part == 0) alpha[EE + e0 + row] = 1.f / (1.f + __expf(-(s + arb2[0]))); }
}

// ---------------- graph-conv v3: h1 = lrelu(P1[i1]+P2[i2]) -> GEMM2 -> segment scan ----------------
__global__ __launch_bounds__(256) void k_gc3(const float* __restrict__ P1, const float* __restrict__ P2,
    const int2* __restrict__ sidx, const float* __restrict__ alphaS, const u16* __restrict__ wt2,
    const float* __restrict__ b2, float* __restrict__ num)
{
  __shared__ __align__(16) char smem[51712];
  int*   nid  = (int*)(smem + 50176);
  int*   i2s  = (int*)(smem + 50688);
  float* alph = (float*)(smem + 51200);
  const int tid = threadIdx.x;
  const int row0 = blockIdx.x * 128;
  if (tid < 128){
    int2 p = sidx[row0 + tid];
    nid[tid] = p.x; i2s[tid] = p.y;
    alph[tid] = alphaS[row0 + tid];
  }
  __syncthreads();
  for (int j = tid; j < 128*24; j += 256){
    int r = j / 24, q = j - (j/24)*24;
    int c8 = q * 8;
    const float* p1 = P1 + (size_t)nid[r]*192 + c8;
    const float* p2 = P2 + (size_t)i2s[r]*192 + c8;
    float4 a0 = *(const float4*)p1, a1 = *(const float4*)(p1 + 4);
    float4 b0 = *(const float4*)p2, b1 = *(const float4*)(p2 + 4);
    u16 pk[8];
    pk[0]=f2bf(lrelu(a0.x+b0.x)); pk[1]=f2bf(lrelu(a0.y+b0.y));
    pk[2]=f2bf(lrelu(a0.z+b0.z)); pk[3]=f2bf(lrelu(a0.w+b0.w));
    pk[4]=f2bf(lrelu(a1.x+b1.x)); pk[5]=f2bf(lrelu(a1.y+b1.y));
    pk[6]=f2bf(lrelu(a1.z+b1.z)); pk[7]=f2bf(lrelu(a1.w+b1.w));
    *(bf16x8*)(smem + swzb(r*384 + c8*2, r)) = *(bf16x8*)pk;
  }
  __syncthreads();
  const int lane = tid & 63, w = tid >> 6;
  const int wr = w >> 1, wc = w & 1;
  const int r15 = lane & 15;
  const int kb = (lane >> 4) * 16;
  const int ke = (lane >> 4) * 8;
  f32x4 acc2[4][3] = {};
  #pragma unroll
  for (int ks = 0; ks < 6; ks++){
    bf16x8 a[4];
    #pragma unroll
    for (int rt = 0; rt < 4; rt++){
      int row = wr*64 + rt*16 + r15;
      a[rt] = *(const bf16x8*)(smem + swzb(row*384 + ks*64 + kb, row));
    }
    #pragma unroll
    for (int ct = 0; ct < 3; ct++){
      int n = wc*48 + ct*16 + r15;
      bf16x8 b = *(const bf16x8*)(wt2 + n*192 + ks*32 + ke);
      #pragma unroll
      for (int rt = 0; rt < 4; rt++)
        acc2[rt][ct] = __builtin_amdgcn_mfma_f32_16x16x32_bf16(a[rt], b, acc2[rt][ct], 0, 0, 0);
    }
  }
  __syncthreads();
  #pragma unroll
  for (int ct = 0; ct < 3; ct++){
    int col = wc*48 + ct*16 + r15;
    float bs = b2[col];
    #pragma unroll
    for (int rt = 0; rt < 4; rt++){
      #pragma unroll
      for (int q = 0; q < 4; q++){
        int row = wr*64 + rt*16 + (lane >> 4)*4 + q;
        *(float*)(smem + row*392 + col*4) = alph[row] * lrelu(acc2[rt][ct][q] + bs);
      }
    }
  }
  __syncthreads();
  if (tid < 192){
    int hf = tid / 96;
    int c = tid - hf*96;
    int rbeg = hf*64, rend = rbeg + 64;
    float accv = 0.f;
    int cur = nid[rbeg];
    for (int r = rbeg; r < rend; r++){
      int n2 = nid[r];
      if (n2 != cur){ atomicAdd(num + cur*96 + c, accv); accv = 0.f; cur = n2; }
      accv += *(const float*)(smem + r*392 + c*4);
    }
    atomicAdd(num + cur*96 + c, accv);
  }
}

// the N rows with ind1=ind2=0 are identical: compute once, add 2048x
__global__ __launch_bounds__(256) void k_gcnode0(const float* __restrict__ h,
    const float* __restrict__ W1, const float* __restrict__ b1,
    const float* __restrict__ W2, const float* __restrict__ b2, float* __restrict__ num)
{
  __shared__ float in_s[192], h1_s[192];
  int t = threadIdx.x;
  if (t < 192) in_s[t] = h[t % 96];
  __syncthreads();
  if (t < 192){
    float s = b1[t];
    for (int k = 0; k < 192; k++) s += in_s[k] * W1[k*192 + t];
    h1_s[t] = lrelu(s);
  }
  __syncthreads();
  if (t < 96){
    float s = b2[t];
    for (int k = 0; k < 192; k++) s += h1_s[k] * W2[k*96 + t];
    num[t] += 2048.f * lrelu(s);
  }
}

__global__ __launch_bounds__(256) void k_hupd(const float* __restrict__ num, const float* __restrict__ den,
                                              float* __restrict__ h){
  int i = blockIdx.x * 256 + threadIdx.x;
  h[i] = num[i] / (den[i / 96] + 1e-8f);
}

// ---------------- final predictor v2 ----------------
__global__ __launch_bounds__(256) void k_final2(const float* __restrict__ hp1, const float* __restrict__ hp2,
    const int* __restrict__ ei, const u16* __restrict__ efnn, const float* __restrict__ efr,
    const float* __restrict__ es, const u16* __restrict__ enc,
    const float* __restrict__ enw2, const float* __restrict__ enb2, float* __restrict__ out)
{
  __shared__ __align__(16) char smem[38144];
  float* etb = (float*)(smem + 12288);
  float* w2s = (float*)(smem + 37120);
  int*   eix = (int*)  (smem + 37504);
  const int tid = threadIdx.x;
  const int e0 = blockIdx.x * 64;
  for (int j = tid; j < 768; j += 256){
    int r = j / 12, q = j - (j/12)*12;
    int e = e0 + r;
    bf16x8 v;
    if (q < 8){
      v = *(const bf16x8*)(efnn + (size_t)e*64 + q*8);
    } else if (q < 10){
      u16 pk[8];
      #pragma unroll
      for (int i = 0; i < 8; i++){
        int cc = (q - 8)*8 + i;
        pk[i] = (cc < 12) ? f2bf((efr[(size_t)e*12 + cc] + 1e-4f) / es[cc]) : (u16)0;
      }
      v = *(bf16x8*)pk;
    } else {
      v = bf16x8{0,0,0,0,0,0,0,0};
    }
    *(bf16x8*)(smem + swzb(r*192 + q*16, r)) = v;
  }
  if (tid < 96) w2s[tid] = enw2[tid];
  if (tid < 64){ eix[2*tid] = ei[2*(e0+tid)]; eix[2*tid+1] = ei[2*(e0+tid)+1]; }
  __syncthreads();
  const int lane = tid & 63, w = tid >> 6;
  const int r15 = lane & 15;
  f32x4 acc[6] = {};
  tile_gemm_gb<6,3,192>(smem, w*16*192, enc, 96, lane, acc);
  #pragma unroll
  for (int ct = 0; ct < 6; ct++){
    int col = ct*16 + r15;
    #pragma unroll
    for (int q = 0; q < 4; q++){
      int row = w*16 + (lane >> 4)*4 + q;
      etb[row*97 + col] = acc[ct][q];
    }
  }
  __syncthreads();
  int r = tid >> 2, part = tid & 3;
  int s1 = eix[2*r], s2 = eix[2*r + 1];
  const float* p1 = hp1 + (size_t)s1*96 + part*24;
  const float* p2 = hp2 + (size_t)s2*96 + part*24;
  const float* et = etb + r*97 + part*24;
  const float* wz = w2s + part*24;
  float s = 0.f;
  #pragma unroll
  for (int i = 0; i < 24; i++){
    float v = et[i] + p1[i] + p2[i];
    s += lrelu(v) * wz[i];
  }
  s += __shfl_xor(s, 1); s += __shfl_xor(s, 2);
  if (part == 0) out[e0 + r] = 1.f / (1.f + __expf(-(s + enb2[0])));
}

// ---------------- host ----------------
extern "C" void kernel_launch(void* const* d_in, const int* in_sizes, int n_in,
                              void* d_out, int out_size, void* d_ws, size_t ws_size,
                              hipStream_t stream) {
  (void)in_sizes; (void)n_in; (void)out_size; (void)ws_size;
  const float* X      = (const float*)d_in[0];
  const float* EFR    = (const float*)d_in[1];
  const int*   EI     = (const int*)  d_in[2];
  const float* NS     = (const float*)d_in[3];
  const float* ES     = (const float*)d_in[4];
  const float* IN_W1  = (const float*)d_in[5];
  const float* IN_B1  = (const float*)d_in[6];
  const float* IN_W2  = (const float*)d_in[7];
  const float* IN_B2  = (const float*)d_in[8];
  const float* QKV_W  = (const float*)d_in[9];
  const float* QKV_B  = (const float*)d_in[10];
  const float* OUT_W  = (const float*)d_in[11];
  const float* OUT_B  = (const float*)d_in[12];
  const float* LN1S   = (const float*)d_in[13];
  const float* LN1B   = (const float*)d_in[14];
  const float* FFW1   = (const float*)d_in[15];
  const float* FFB1   = (const float*)d_in[16];
  const float* FFW2   = (const float*)d_in[17];
  const float* FFB2   = (const float*)d_in[18];
  const float* LN2S   = (const float*)d_in[19];
  const float* LN2B   = (const float*)d_in[20];
  const float* EIN_W1 = (const float*)d_in[21];
  const float* EIN_B1 = (const float*)d_in[22];
  const float* EIN_W2 = (const float*)d_in[23];
  const float* EIN_B2 = (const float*)d_in[24];
  const float* AD_W1  = (const float*)d_in[25];
  const float* AD_B1  = (const float*)d_in[26];
  const float* AD_W2  = (const float*)d_in[27];
  const float* AD_B2  = (const float*)d_in[28];
  const float* AR_W1  = (const float*)d_in[29];
  const float* AR_B1  = (const float*)d_in[30];
  const float* AR_W2  = (const float*)d_in[31];
  const float* AR_B2  = (const float*)d_in[32];
  const float* GC_W1  = (const float*)d_in[33];
  const float* GC_B1  = (const float*)d_in[34];
  const float* GC_W2  = (const float*)d_in[35];
  const float* GC_B2  = (const float*)d_in[36];
  const float* EN_W1  = (const float*)d_in[37];
  const float* EN_B1  = (const float*)d_in[38];
  const float* EN_W2  = (const float*)d_in[39];
  const float* EN_B2  = (const float*)d_in[40];

  char* ws = (char*)d_ws;
  u16*   pool   = (u16*)  (ws + WS_WT);
  u16*   efnn   = (u16*)  (ws + WS_EFNN);
  float* alpha  = (float*)(ws + WS_ALPHA);
  float* h      = (float*)(ws + WS_H);
  float* qkvb   = (float*)(ws + WS_QKV);
  float* obuf   = (float*)(ws + WS_OBUF);
  float* tmpA   = (float*)(ws + WS_TMPA);
  float* tmpB   = (float*)(ws + WS_TMPB);
  float* x1     = (float*)(ws + WS_X1);
  float* num    = (float*)(ws + WS_NUM);
  float* den    = (float*)(ws + WS_DEN);
  float* xs     = (float*)(ws + WS_XS);
  int2*  sidx   = (int2*) (ws + WS_SIDX);
  float* alphaS = (float*)(ws + WS_ALPS);
  int*   cnt    = (int*)  (ws + WS_CNT);
  int*   offs   = (int*)  (ws + WS_OFFS);
  float* P1     = (float*)(ws + WS_QKV);   // reuse (encoders done before gc)
  float* P2     = (float*)(ws + WS_TMPB);
  float* hp1    = (float*)(ws + WS_OBUF);
  float* hp2    = (float*)(ws + WS_TMPA);
  float* kvp    = (float*)(ws + WS_ALPHA); // reuse: alpha dead after k_scatter

  // ---- weight conversion jobs ----
  CvtJobs jb;
  int idx = 0, cum = 0;
  auto addjob = [&](const float* s, int K, int Nc, int Kp){
    jb.src[idx] = s; jb.K[idx] = K; jb.Nc[idx] = Nc; jb.Kp[idx] = Kp;
    jb.cum[idx] = cum; cum += Nc * Kp; idx++;
  };
  addjob(IN_W1, 19, 96, 32);
  addjob(IN_W2, 96, 96, 96);
  for (int l = 0; l < 3; l++) addjob(QKV_W + (size_t)l*96*288, 96, 288, 96);
  for (int l = 0; l < 3; l++) addjob(OUT_W + (size_t)l*96*96,  96, 96,  96);
  for (int l = 0; l < 3; l++) addjob(FFW1  + (size_t)l*96*192, 96, 192, 96);
  for (int l = 0; l < 3; l++) addjob(FFW2  + (size_t)l*192*96, 192, 96, 192);
  addjob(EIN_W1, 12, 64, 32);
  addjob(EIN_W2, 64, 64, 64);
  addjob(AD_W1,  64, 64, 64);
  addjob(AR_W1,  64, 64, 64);
  for (int i = 0; i < 2; i++){
    addjob(GC_W1 + (size_t)i*192*192,          96, 192, 96);
    addjob(GC_W1 + (size_t)i*192*192 + 96*192, 96, 192, 96);
  }
  for (int i = 0; i < 2; i++) addjob(GC_W2 + (size_t)i*192*96, 192, 96, 192);
  addjob(EN_W1,            96, 96, 96);
  addjob(EN_W1 + 96*96,    96, 96, 96);
  addjob(EN_W1 + 192*96,   76, 96, 96);
  jb.cum[idx] = cum;

  k_cvt<<<(POOL_TOT + 255)/256, 256, 0, stream>>>(jb, pool);

  // ---- node embedding ----
  k_xscale<<<(NN*19 + 255)/256, 256, 0, stream>>>(X, NS, xs);
  k_gemm<6,1,1><<<32, 256, 0, stream>>>(xs, 19, pool + IN1T, IN_B1, tmpA, nullptr);
  k_gemm<6,3,1><<<32, 256, 0, stream>>>(tmpA, 96, pool + IN2T, IN_B2, h, nullptr);

  // ---- edge MLPs + attention weights ----
  k_edge<<<EE/64, 256, 0, stream>>>(EFR, ES, pool, EIN_B1, EIN_B2,
                                    AD_B1, AD_W2, AD_B2, AR_B1, AR_W2, AR_B2, efnn, alpha);

  // ---- destination sort + den ----
  (void)hipMemsetAsync(cnt, 0, NN*4, stream);
  k_hist<<<(2*EE)/256, 256, 0, stream>>>(EI, cnt);
  k_scan<<<1, 256, 0, stream>>>(cnt, offs);
  (void)hipMemsetAsync(cnt, 0, NN*4, stream);
  k_scatter<<<(2*EE)/256, 256, 0, stream>>>(EI, alpha, offs, cnt, sidx, alphaS);
  k_dens<<<NN/4, 256, 0, stream>>>(offs, alphaS, den);

  // ---- 3 encoder layers ----
  for (int l = 0; l < 3; l++){
    k_gemm<18,3,0,1><<<32, 256, 0, stream>>>(h, 96, pool + QKVT + l*27648, QKV_B + l*288, qkvb, kvp);
    k_attn5<<<1536, 256, 0, stream>>>(qkvb, kvp, obuf);
    k_gemm<6,3,0><<<32, 256, 0, stream>>>(obuf, 96, pool + OUTT + l*9216, OUT_B + l*96, tmpA, nullptr);
    k_ln<<<512, 256, 0, stream>>>(h, tmpA, LN1S + l*96, LN1B + l*96, x1);
    k_gemm<12,3,2><<<32, 256, 0, stream>>>(x1, 96, pool + FF1T + l*18432, FFB1 + l*192, tmpB, nullptr);
    k_gemm<6,6,0><<<32, 256, 0, stream>>>(tmpB, 192, pool + FF2T + l*18432, FFB2 + l*96, tmpA, nullptr);
    k_ln<<<512, 256, 0, stream>>>(x1, tmpA, LN2S + l*96, LN2B + l*96, h);
  }

  // ---- 2 graph-conv iterations ----
  for (int it = 0; it < 2; it++){
    k_gemm<12,3,0><<<32, 256, 0, stream>>>(h, 96, pool + GC1T + it*36864,         nullptr,        P1, nullptr);
    k_gemm<12,3,0><<<32, 256, 0, stream>>>(h, 96, pool + GC1T + it*36864 + 18432, GC_B1 + it*192, P2, nullptr);
    (void)hipMemsetAsync(num, 0, NN*96*4, stream);
    k_gc3<<<(2*EE)/128, 256, 0, stream>>>(P1, P2, sidx, alphaS,
        pool + GC2T + it*18432, GC_B2 + it*96, num);
    k_gcnode0<<<1, 256, 0, stream>>>(h, GC_W1 + (size_t)it*192*192, GC_B1 + it*192,
                                     GC_W2 + (size_t)it*192*96, GC_B2 + it*96, num);
    k_hupd<<<(NN*96)/256, 256, 0, stream>>>(num, den, h);
  }

  // ---- final predictor ----
  k_gemm<6,3,0><<<32, 256, 0, stream>>>(h, 96, pool + ENAT, nullptr, hp1, nullptr);
  k_gemm<6,3,0><<<32, 256, 0, stream>>>(h, 96, pool + ENBT, EN_B1, hp2, nullptr);
  k_final2<<<EE/64, 256, 0, stream>>>(hp1, hp2, EI, efnn, EFR, ES,
                                      pool + ENCT, EN_W2, EN_B2, (float*)d_out);
}